// Round 11
// baseline (657.005 us; speedup 1.0000x reference)
//
#include <hip/hip_runtime.h>
#include <hip/hip_bf16.h>
#include <math.h>

#define NUM_USERS 60000
#define NUM_ITEMS 30000
#define DD 64
#define SEMD 1024
#define HIDD 32
#define KNBR 32
#define NNZE 2000000
#define NLAYERS 3
#define BBATCH 4096
#define LALPHA 0.2f
#define NTOT (NUM_USERS + NUM_ITEMS)
#define SCAN_NB ((NTOT + 1023) / 1024)  // 88
#define NBKT 704                         // buckets = row>>7
#define BCAP 3328                        // bucket LDS cap

typedef unsigned short ushort_t;
typedef short s16x8 __attribute__((ext_vector_type(8)));
typedef float f32x4 __attribute__((ext_vector_type(4)));

__device__ __forceinline__ ushort_t f2bf(float x) {  // RNE
    unsigned u = __float_as_uint(x);
    return (ushort_t)((u + 0x7FFFu + ((u >> 16) & 1u)) >> 16);
}
__device__ __forceinline__ float bf2f(ushort_t s) {
    return __uint_as_float(((unsigned)s) << 16);
}

// async global->LDS DMA, 16B per lane; LDS dest = base + lane*16 (wave-uniform base)
#define GLD_LDS16(gp, lp)                                                  \
    __builtin_amdgcn_global_load_lds(                                      \
        (const __attribute__((address_space(1))) void*)(gp),               \
        (__attribute__((address_space(3))) void*)(lp), 16, 0, 0)

// truncation split of 8 floats into bf16 hi/lo fragments
__device__ __forceinline__ void split8(const float4& f0, const float4& f1,
                                       s16x8& hi, s16x8& lo) {
    float f[8] = {f0.x, f0.y, f0.z, f0.w, f1.x, f1.y, f1.z, f1.w};
#pragma unroll
    for (int j = 0; j < 8; ++j) {
        unsigned u = __float_as_uint(f[j]);
        hi[j] = (short)(u >> 16);
        lo[j] = (short)(__float_as_uint(f[j] - __uint_as_float(u & 0xFFFF0000u)) >> 16);
    }
}

// ---------- W split (transposed bf16 hi/lo) + fused wa1/wa2 ----------
__global__ __launch_bounds__(256) void wsplit(const float* __restrict__ Wu,
                                              const float* __restrict__ Ws,
                                              ushort_t* __restrict__ hiU, ushort_t* __restrict__ loU,
                                              ushort_t* __restrict__ hiS, ushort_t* __restrict__ loS,
                                              const float* __restrict__ W_att,
                                              const float* __restrict__ a_att,
                                              float* __restrict__ wa1,
                                              float* __restrict__ wa2) {
    if (blockIdx.x == 512) {  // fused prep_wa
        int t = threadIdx.x;
#pragma unroll
        for (int r = 0; r < 4; ++r) {
            int k = t * 4 + r;
            float d1 = 0.f, d2 = 0.f;
#pragma unroll
            for (int h = 0; h < HIDD; ++h) {
                float w = W_att[k * HIDD + h];
                d1 += w * a_att[h];
                d2 += w * a_att[HIDD + h];
            }
            wa1[k] = d1;
            wa2[k] = d2;
        }
        return;
    }
    int id = blockIdx.x * 256 + threadIdx.x;  // 0..131071
    int i = id & 65535;
    int k = i & 1023;
    int c = i >> 10;
    float x = (id < 65536) ? Wu[(size_t)k * DD + c] : Ws[(size_t)k * DD + c];
    ushort_t h = f2bf(x);
    ushort_t l = f2bf(x - bf2f(h));
    ushort_t* dh = (id < 65536) ? hiU : hiS;
    ushort_t* dl = (id < 65536) ? loU : loS;
    dh[(size_t)c * SEMD + k] = h;
    dl[(size_t)c * SEMD + k] = l;
}

// ---------- MFMA bf16x3 GEMM: 1KB-burst DMA staging, counted vmcnt ----------
// Block = 32 rows x 64 cols, 4 waves. Wave w: rows [(w>>1)*16,+16) x cols [(w&1)*32,+32).
// K in 4 chunks of 256. Staging: one DMA issue = one row's 1KB chunk, 64 lanes
// contiguous; per-lane source float4 index = lane ^ j (j = row%8) pre-swizzles
// LDS content within the SAME 1KB window (burst preserved, bank conflicts ~2-way).
// Read side uses the same XOR. Steady-state vmcnt(8): next chunk stays in flight.
template <bool DOS12>
__global__ __launch_bounds__(256) void gemm_mfma(
    const float* __restrict__ A,
    const ushort_t* __restrict__ WThi,
    const ushort_t* __restrict__ WTlo,
    const float* __restrict__ bias,
    const float* __restrict__ emb,
    float* __restrict__ out32,
    ushort_t* __restrict__ out16,
    int M,
    const float* __restrict__ wa1,
    const float* __restrict__ wa2,
    float* __restrict__ s1,
    float* __restrict__ s2) {
    __shared__ float As0[32 * 256];   // 32KB, chunk buffer 0
    __shared__ float As1[32 * 256];   // 32KB, chunk buffer 1

    const int tid = threadIdx.x;
    const int lane = tid & 63;
    const int w = tid >> 6;
    const int l15 = lane & 15;
    const int l4 = lane >> 4;
    const int rb = blockIdx.x * 32;

    // DMA source pointers: wave w stages local rows w*8+j (j=0..7); lane covers
    // float4 index (lane ^ j) of the row's 1KB chunk -> contiguous 1KB burst.
    const float* gsrc[8];
#pragma unroll
    for (int j = 0; j < 8; ++j) {
        int gr = min(rb + w * 8 + j, M - 1);
        gsrc[j] = A + (size_t)gr * SEMD + ((lane ^ j) * 4);
    }
    // W fragment pointers: wave w covers cols (w&1)*32 + cg*16 + l15, cg=0..1
    const ushort_t* bhp[2];
    const ushort_t* blp[2];
#pragma unroll
    for (int cg = 0; cg < 2; ++cg) {
        int off = ((w & 1) * 32 + cg * 16 + l15) * SEMD + l4 * 8;
        bhp[cg] = WThi + off;
        blp[cg] = WTlo + off;
    }

    f32x4 acc[2] = {};
    float s1p = 0.f, s2p = 0.f;

    auto stage = [&](int c, float* dst) {
#pragma unroll
        for (int j = 0; j < 8; ++j)
            GLD_LDS16(gsrc[j] + c * 256, dst + (w * 8 + j) * 256);
    };

    // prologue: chunks 0,1 in flight
    stage(0, As0);
    stage(1, As1);

    const int rloc = (w >> 1) * 16 + l15;   // local A row this lane consumes
    const int rsw = rloc & 7;               // read-side swizzle (= stage j%8)
    const float* lb0 = As0 + rloc * 256;
    const float* lb1 = As1 + rloc * 256;

#pragma unroll
    for (int c = 0; c < 4; ++c) {
        if (c < 3)
            asm volatile("s_waitcnt vmcnt(8)" ::: "memory");   // chunk c done, c+1 in flight
        else
            asm volatile("s_waitcnt vmcnt(0)" ::: "memory");
        __builtin_amdgcn_s_barrier();
        asm volatile("" ::: "memory");
        const float* lb = (c & 1) ? lb1 : lb0;
#pragma unroll
        for (int ks = 0; ks < 8; ++ks) {
            int f0 = ks * 8 + l4 * 2;
            float4 a0 = *(const float4*)(lb + ((f0 ^ rsw) * 4));
            float4 a1 = *(const float4*)(lb + (((f0 + 1) ^ rsw) * 4));
            int kk = c * 256 + ks * 32;
            if (DOS12) {
                float4 w1a = *(const float4*)(wa1 + kk + l4 * 8);
                float4 w1b = *(const float4*)(wa1 + kk + l4 * 8 + 4);
                float4 w2a = *(const float4*)(wa2 + kk + l4 * 8);
                float4 w2b = *(const float4*)(wa2 + kk + l4 * 8 + 4);
                s1p += a0.x * w1a.x + a0.y * w1a.y + a0.z * w1a.z + a0.w * w1a.w
                     + a1.x * w1b.x + a1.y * w1b.y + a1.z * w1b.z + a1.w * w1b.w;
                s2p += a0.x * w2a.x + a0.y * w2a.y + a0.z * w2a.z + a0.w * w2a.w
                     + a1.x * w2b.x + a1.y * w2b.y + a1.z * w2b.z + a1.w * w2b.w;
            }
            s16x8 ah, al;
            split8(a0, a1, ah, al);
#pragma unroll
            for (int cg = 0; cg < 2; ++cg) {
                s16x8 bh = *(const s16x8*)(bhp[cg] + kk);
                s16x8 bl = *(const s16x8*)(blp[cg] + kk);
                acc[cg] = __builtin_amdgcn_mfma_f32_16x16x32_bf16(ah, bh, acc[cg], 0, 0, 0);
                acc[cg] = __builtin_amdgcn_mfma_f32_16x16x32_bf16(ah, bl, acc[cg], 0, 0, 0);
                acc[cg] = __builtin_amdgcn_mfma_f32_16x16x32_bf16(al, bh, acc[cg], 0, 0, 0);
            }
        }
        asm volatile("" ::: "memory");
        __builtin_amdgcn_s_barrier();
        if (c < 2) stage(c + 2, (c & 1) ? As1 : As0);
    }

    if (DOS12) {
        // waves 0/1 (and 2/3) compute identical s1p for their shared rows; one stores.
        float v1 = s1p, v2 = s2p;
        v1 += __shfl_xor(v1, 16); v1 += __shfl_xor(v1, 32);
        v2 += __shfl_xor(v2, 16); v2 += __shfl_xor(v2, 32);
        int r = rb + rloc;
        if (l4 == 0 && (w & 1) == 0 && r < M) {
            s1[r] = v1;
            s2[r] = v2;
        }
    }

    // epilogue: D col = (w&1)*32 + cg*16 + l15, row = rb + (w>>1)*16 + l4*4 + j
#pragma unroll
    for (int cg = 0; cg < 2; ++cg) {
        int col = (w & 1) * 32 + cg * 16 + l15;
        float b = bias[col];
#pragma unroll
        for (int j = 0; j < 4; ++j) {
            int grow = rb + (w >> 1) * 16 + l4 * 4 + j;
            if (grow < M) {
                float x = acc[cg][j] + b;
                float e = x > 0.f ? x : (expf(x) - 1.f);
                float v = (emb[(size_t)grow * DD + col] + e) * 0.5f;
                out32[(size_t)grow * DD + col] = v;
                out16[(size_t)grow * DD + col] = f2bf(v);
            }
        }
    }
}

// ---------- attention + h' + merge: one wave per item row ----------
__global__ __launch_bounds__(256) void att_kernel(const int* __restrict__ adj,
                                                  const float* __restrict__ s1,
                                                  const float* __restrict__ s2,
                                                  const float* __restrict__ M0,
                                                  const ushort_t* __restrict__ M0h,
                                                  ushort_t* __restrict__ cur16,
                                                  float* __restrict__ sum_) {
    int gid = blockIdx.x * 256 + threadIdx.x;
    int row = gid >> 6;
    int lane = gid & 63;
    if (row >= NUM_ITEMS) return;
    int kk = lane & 31;
    int col = adj[(size_t)row * KNBR + kk];
    float e = s1[col] + s2[row];
    e = e > 0.f ? e : LALPHA * e;
    float mx = e;
#pragma unroll
    for (int m = 1; m < 32; m <<= 1) mx = fmaxf(mx, __shfl_xor(mx, m));
    float ex = expf(e - mx);
    float ssum = ex;
#pragma unroll
    for (int m = 1; m < 32; m <<= 1) ssum += __shfl_xor(ssum, m);
    float wgt = ex / ssum;
    float h = 0.f;
#pragma unroll
    for (int k = 0; k < 32; ++k) {
        int ck = __builtin_amdgcn_readlane(col, k);
        float wk = __uint_as_float((unsigned)__builtin_amdgcn_readlane(
            (int)__float_as_uint(wgt), k));
        h += wk * bf2f(M0h[(size_t)ck * DD + lane]);
    }
    float eh = h > 0.f ? h : (expf(h) - 1.f);
    float v = (M0[(size_t)row * DD + lane] + eh) * 0.5f;
    size_t o = (size_t)(NUM_USERS + row) * DD + lane;
    cur16[o] = f2bf(v);
    sum_[o] = v;
}

// ---------- CSR build ----------
__global__ __launch_bounds__(256) void hist_kernel(const int* __restrict__ rows,
                                                   int* __restrict__ cnt) {
    int e = blockIdx.x * 256 + threadIdx.x;
    if (e < NNZE) atomicAdd(&cnt[rows[e]], 1);
}

__global__ __launch_bounds__(256) void scan_blocksums(const int* __restrict__ cnt,
                                                      int* __restrict__ bsum) {
    __shared__ int ws[4];
    int tid = threadIdx.x;
    int base = blockIdx.x * 1024 + tid * 4;
    int s = 0;
    if (base + 3 < NTOT) {
        int4 v = *(const int4*)(cnt + base);
        s = v.x + v.y + v.z + v.w;
    } else {
        for (int i = 0; i < 4; ++i)
            if (base + i < NTOT) s += cnt[base + i];
    }
#pragma unroll
    for (int m = 32; m; m >>= 1) s += __shfl_xor(s, m);
    if ((tid & 63) == 0) ws[tid >> 6] = s;
    __syncthreads();
    if (tid == 0) bsum[blockIdx.x] = ws[0] + ws[1] + ws[2] + ws[3];
}

__global__ __launch_bounds__(128) void scan_bsums(const int* __restrict__ bsum,
                                                  int* __restrict__ boff,
                                                  int* __restrict__ rowptr) {
    __shared__ int sh[128];
    int t = threadIdx.x;
    int v = (t < SCAN_NB) ? bsum[t] : 0;
    sh[t] = v;
    __syncthreads();
    for (int off = 1; off < 128; off <<= 1) {
        int x = (t >= off) ? sh[t - off] : 0;
        __syncthreads();
        sh[t] += x;
        __syncthreads();
    }
    if (t < SCAN_NB) boff[t] = (t == 0) ? 0 : sh[t - 1];
    if (t == 127) rowptr[NTOT] = sh[SCAN_NB - 1];
}

__global__ __launch_bounds__(256) void scan_write(const int* __restrict__ cnt,
                                                  const int* __restrict__ boff,
                                                  int* __restrict__ rowptr,
                                                  int* __restrict__ cursor,
                                                  int* __restrict__ bcursor) {
    __shared__ int wsum[4];
    int tid = threadIdx.x;
    int lane = tid & 63;
    int wave = tid >> 6;
    int base = blockIdx.x * 1024 + tid * 4;

    int e0 = 0, e1 = 0, e2 = 0, e3 = 0;
    if (base + 3 < NTOT) {
        int4 v = *(const int4*)(cnt + base);
        e0 = v.x; e1 = v.y; e2 = v.z; e3 = v.w;
    } else {
        if (base + 0 < NTOT) e0 = cnt[base + 0];
        if (base + 1 < NTOT) e1 = cnt[base + 1];
        if (base + 2 < NTOT) e2 = cnt[base + 2];
    }
    int tsum = e0 + e1 + e2 + e3;

    int s = tsum;
#pragma unroll
    for (int off = 1; off < 64; off <<= 1) {
        int x = __shfl_up(s, off);
        if (lane >= off) s += x;
    }
    if (lane == 63) wsum[wave] = s;
    __syncthreads();
    int woff = 0;
    for (int ww = 0; ww < 4; ++ww)
        if (ww < wave) woff += wsum[ww];
    __syncthreads();
    int excl = boff[blockIdx.x] + woff + (s - tsum);

    int4 r;
    r.x = excl;
    r.y = excl + e0;
    r.z = excl + e0 + e1;
    r.w = excl + e0 + e1 + e2;
    if (base + 3 < NTOT) {
        *(int4*)(rowptr + base) = r;
        *(int4*)(cursor + base) = r;
    } else {
        if (base + 0 < NTOT) { rowptr[base + 0] = r.x; cursor[base + 0] = r.x; }
        if (base + 1 < NTOT) { rowptr[base + 1] = r.y; cursor[base + 1] = r.y; }
        if (base + 2 < NTOT) { rowptr[base + 2] = r.z; cursor[base + 2] = r.z; }
    }
    if ((base & 127) == 0 && base < NTOT) bcursor[base >> 7] = r.x;
}

// ---------- Phase A: bin edges by row>>7, grouped writes ----------
__global__ __launch_bounds__(256) void binA(const int* __restrict__ grows,
                                            const int* __restrict__ gcols,
                                            const float* __restrict__ gvals,
                                            int* __restrict__ bcursor,
                                            int2* __restrict__ temp) {
    __shared__ int hist[NBKT];
    __shared__ int gcur[NBKT];
    int tid = threadIdx.x;
    int base = blockIdx.x * 4096;
    for (int i = tid; i < NBKT; i += 256) hist[i] = 0;
    __syncthreads();
#pragma unroll 4
    for (int j = 0; j < 16; ++j) {
        int e = base + j * 256 + tid;
        if (e < NNZE) atomicAdd(&hist[grows[e] >> 7], 1);
    }
    __syncthreads();
    for (int b = tid; b < NBKT; b += 256) {
        int n = hist[b];
        gcur[b] = n ? atomicAdd(&bcursor[b], n) : 0;
    }
    __syncthreads();
#pragma unroll 4
    for (int j = 0; j < 16; ++j) {
        int e = base + j * 256 + tid;
        if (e < NNZE) {
            int r = grows[e];
            int b = r >> 7;
            int pos = atomicAdd(&gcur[b], 1);
            temp[pos] = make_int2((gcols[e] & 0x1FFFF) | ((r & 127) << 17),
                                  __float_as_int(gvals[e]));
        }
    }
}

// ---------- Phase B: in-place within-bucket re-sort to CSR order ----------
__global__ __launch_bounds__(256) void binB(const int* __restrict__ rowptr,
                                            int* __restrict__ cursor,
                                            int2* __restrict__ sedge) {
    __shared__ int2 ebuf[BCAP];
    int b = blockIdx.x;
    int start = rowptr[b << 7];
    int end = rowptr[min((b + 1) << 7, NTOT)];
    int n = min(end - start, BCAP);
    for (int i = threadIdx.x; i < n; i += 256) ebuf[i] = sedge[start + i];
    __syncthreads();
    for (int i = threadIdx.x; i < n; i += 256) {
        int2 w = ebuf[i];
        int r = (b << 7) + ((w.x >> 17) & 127);
        int pos = atomicAdd(&cursor[r], 1);
        sedge[pos] = make_int2(w.x & 0x1FFFF, w.y);
    }
}

// ---------- SpMM layer (pull, scalar edge loads): one wave per row ----------
__global__ __launch_bounds__(256) void spmm16(const int* __restrict__ rowptr,
                                              const int2* __restrict__ sedge,
                                              const ushort_t* __restrict__ cur,
                                              ushort_t* __restrict__ nxt,
                                              float* __restrict__ sum_) {
    int row = __builtin_amdgcn_readfirstlane((blockIdx.x * 256 + threadIdx.x) >> 6);
    int lane = threadIdx.x & 63;
    if (row >= NTOT) return;
    int i = rowptr[row];
    int e = rowptr[row + 1];
    float acc = 0.f;
    for (; i + 4 <= e; i += 4) {
        int2 ed0 = sedge[i];
        int2 ed1 = sedge[i + 1];
        int2 ed2 = sedge[i + 2];
        int2 ed3 = sedge[i + 3];
        float x0 = bf2f(cur[(size_t)ed0.x * DD + lane]);
        float x1 = bf2f(cur[(size_t)ed1.x * DD + lane]);
        float x2 = bf2f(cur[(size_t)ed2.x * DD + lane]);
        float x3 = bf2f(cur[(size_t)ed3.x * DD + lane]);
        acc += __int_as_float(ed0.y) * x0;
        acc += __int_as_float(ed1.y) * x1;
        acc += __int_as_float(ed2.y) * x2;
        acc += __int_as_float(ed3.y) * x3;
    }
    for (; i < e; ++i) {
        int2 ed = sedge[i];
        acc += __int_as_float(ed.y) * bf2f(cur[(size_t)ed.x * DD + lane]);
    }
    size_t o = (size_t)row * DD + lane;
    if (nxt) nxt[o] = f2bf(acc);
    sum_[o] += acc;
}

// ---------- final gather + dot ----------
__global__ __launch_bounds__(256) void gamma_kernel(const int* __restrict__ users,
                                                    const int* __restrict__ items,
                                                    const float* __restrict__ sum_,
                                                    float* __restrict__ out) {
    int gid = blockIdx.x * 256 + threadIdx.x;
    int b = gid >> 6;
    int lane = gid & 63;
    if (b >= BBATCH) return;
    int u = users[b];
    int it = items[b];
    float pu = sum_[(size_t)u * DD + lane];
    float pi = sum_[(size_t)(NUM_USERS + it) * DD + lane];
    float p = pu * pi;
#pragma unroll
    for (int m = 32; m; m >>= 1) p += __shfl_xor(p, m);
    if (lane == 0) out[b] = p * 0.0625f;
}

extern "C" void kernel_launch(void* const* d_in, const int* in_sizes, int n_in,
                              void* d_out, int out_size, void* d_ws, size_t ws_size,
                              hipStream_t stream) {
    const int* users = (const int*)d_in[0];
    const int* items = (const int*)d_in[1];
    const int* adj = (const int*)d_in[2];
    const int* grows = (const int*)d_in[3];
    const int* gcols = (const int*)d_in[4];
    const float* gvals = (const float*)d_in[5];
    const float* sem = (const float*)d_in[6];
    const float* usem = (const float*)d_in[7];
    const float* emb_user = (const float*)d_in[8];
    const float* emb_item = (const float*)d_in[9];
    const float* W_sem = (const float*)d_in[10];
    const float* b_sem = (const float*)d_in[11];
    const float* W_usem = (const float*)d_in[12];
    const float* b_usem = (const float*)d_in[13];
    const float* W_att = (const float*)d_in[14];
    const float* a_att = (const float*)d_in[15];
    float* out = (float*)d_out;

    const size_t NE = (size_t)NTOT * DD;          // 5.76M
    const size_t IE = (size_t)NUM_ITEMS * DD;     // 1.92M
    char* p = (char*)d_ws;
    float* sum_ = (float*)p;        p += NE * 4;
    ushort_t* cur16 = (ushort_t*)p; p += NE * 2;
    ushort_t* nxt16 = (ushort_t*)p; p += NE * 2;
    float* M0 = (float*)p;          p += IE * 4;
    ushort_t* M0h = (ushort_t*)p;   p += IE * 2;
    int2* sedge = (int2*)p;         p += (size_t)NNZE * 8;
    ushort_t* WThiU = (ushort_t*)p; p += 65536 * 2;
    ushort_t* WTloU = (ushort_t*)p; p += 65536 * 2;
    ushort_t* WThiS = (ushort_t*)p; p += 65536 * 2;
    ushort_t* WTloS = (ushort_t*)p; p += 65536 * 2;
    float* s1 = (float*)p;          p += NUM_ITEMS * 4;
    float* s2 = (float*)p;          p += NUM_ITEMS * 4;
    float* wa1 = (float*)p;         p += SEMD * 4;
    float* wa2 = (float*)p;         p += SEMD * 4;
    int* cnt = (int*)p;             p += NTOT * 4;
    int* rowptr = (int*)p;          p += (NTOT + 4) * 4;
    int* cursor = (int*)p;          p += NTOT * 4;
    int* bsum = (int*)p;            p += 96 * 4;
    int* boff = (int*)p;            p += 96 * 4;
    int* bcursor = (int*)p;         p += NBKT * 4;

    wsplit<<<513, 256, 0, stream>>>(W_usem, W_sem, WThiU, WTloU, WThiS, WTloS,
                                    W_att, a_att, wa1, wa2);

    gemm_mfma<false><<<(NUM_USERS + 31) / 32, 256, 0, stream>>>(
        usem, WThiU, WTloU, b_usem, emb_user, sum_, cur16, NUM_USERS,
        nullptr, nullptr, nullptr, nullptr);
    gemm_mfma<true><<<(NUM_ITEMS + 31) / 32, 256, 0, stream>>>(
        sem, WThiS, WTloS, b_sem, emb_item, M0, M0h, NUM_ITEMS,
        wa1, wa2, s1, s2);

    att_kernel<<<(NUM_ITEMS * 64 + 255) / 256, 256, 0, stream>>>(adj, s1, s2, M0, M0h,
                                                                 cur16, sum_);

    hipMemsetAsync(cnt, 0, NTOT * sizeof(int), stream);
    hist_kernel<<<(NNZE + 255) / 256, 256, 0, stream>>>(grows, cnt);
    scan_blocksums<<<SCAN_NB, 256, 0, stream>>>(cnt, bsum);
    scan_bsums<<<1, 128, 0, stream>>>(bsum, boff, rowptr);
    scan_write<<<SCAN_NB, 256, 0, stream>>>(cnt, boff, rowptr, cursor, bcursor);
    binA<<<(NNZE + 4095) / 4096, 256, 0, stream>>>(grows, gcols, gvals, bcursor, sedge);
    binB<<<NBKT, 256, 0, stream>>>(rowptr, cursor, sedge);

    ushort_t* cur = cur16;
    ushort_t* nxt = nxt16;
    for (int l = 0; l < NLAYERS; ++l) {
        spmm16<<<(NTOT * 64 + 255) / 256, 256, 0, stream>>>(
            rowptr, sedge, cur, (l == NLAYERS - 1) ? nullptr : nxt, sum_);
        ushort_t* t = cur;
        cur = nxt;
        nxt = t;
    }
    gamma_kernel<<<(BBATCH * 64 + 255) / 256, 256, 0, stream>>>(users, items, sum_, out);
}

// Round 12
// 406.829 us; speedup vs baseline: 1.6149x; 1.6149x over previous
//
#include <hip/hip_runtime.h>
#include <hip/hip_bf16.h>
#include <math.h>

#define NUM_USERS 60000
#define NUM_ITEMS 30000
#define DD 64
#define SEMD 1024
#define HIDD 32
#define KNBR 32
#define NNZE 2000000
#define NLAYERS 3
#define BBATCH 4096
#define LALPHA 0.2f
#define NTOT (NUM_USERS + NUM_ITEMS)
#define NBKT 704                         // buckets = row>>7
#define BCAP 3328                        // bucket LDS cap (+9 sigma)

typedef unsigned short ushort_t;
typedef short s16x8 __attribute__((ext_vector_type(8)));
typedef float f32x4 __attribute__((ext_vector_type(4)));

__device__ __forceinline__ ushort_t f2bf(float x) {  // RNE
    unsigned u = __float_as_uint(x);
    return (ushort_t)((u + 0x7FFFu + ((u >> 16) & 1u)) >> 16);
}
__device__ __forceinline__ float bf2f(ushort_t s) {
    return __uint_as_float(((unsigned)s) << 16);
}

#define CFENCE() asm volatile("" ::: "memory")

// ---------- W split (transposed bf16 hi/lo) + fused wa1/wa2 ----------
__global__ __launch_bounds__(256) void wsplit(const float* __restrict__ Wu,
                                              const float* __restrict__ Ws,
                                              ushort_t* __restrict__ hiU, ushort_t* __restrict__ loU,
                                              ushort_t* __restrict__ hiS, ushort_t* __restrict__ loS,
                                              const float* __restrict__ W_att,
                                              const float* __restrict__ a_att,
                                              float* __restrict__ wa1,
                                              float* __restrict__ wa2) {
    if (blockIdx.x == 512) {  // fused prep_wa
        int t = threadIdx.x;
#pragma unroll
        for (int r = 0; r < 4; ++r) {
            int k = t * 4 + r;
            float d1 = 0.f, d2 = 0.f;
#pragma unroll
            for (int h = 0; h < HIDD; ++h) {
                float w = W_att[k * HIDD + h];
                d1 += w * a_att[h];
                d2 += w * a_att[HIDD + h];
            }
            wa1[k] = d1;
            wa2[k] = d2;
        }
        return;
    }
    int id = blockIdx.x * 256 + threadIdx.x;  // 0..131071
    int i = id & 65535;
    int k = i & 1023;
    int c = i >> 10;
    float x = (id < 65536) ? Wu[(size_t)k * DD + c] : Ws[(size_t)k * DD + c];
    ushort_t h = f2bf(x);
    ushort_t l = f2bf(x - bf2f(h));
    ushort_t* dh = (id < 65536) ? hiU : hiS;
    ushort_t* dl = (id < 65536) ? loU : loS;
    dh[(size_t)c * SEMD + k] = h;
    dl[(size_t)c * SEMD + k] = l;
}

// ---------- MFMA bf16x3 GEMM (R5 structure: LDS staging, reg prefetch, raw barriers) ----------
// BM=64, BK=64, 256 threads (4 waves), each wave 16 rows x 64 cols.
template <bool DOS12>
__global__ __launch_bounds__(256) void gemm_mfma(
    const float* __restrict__ A,
    const ushort_t* __restrict__ WThi,
    const ushort_t* __restrict__ WTlo,
    const float* __restrict__ bias,
    const float* __restrict__ emb,
    float* __restrict__ out32,       // only written when DOS12 (items: M0)
    ushort_t* __restrict__ out16,
    int M,
    const float* __restrict__ wa1,
    const float* __restrict__ wa2,
    float* __restrict__ s1,
    float* __restrict__ s2) {
    __shared__ __align__(16) ushort_t Ah[64 * 64];   // swizzled: byte ^= (row&7)<<4
    __shared__ __align__(16) ushort_t Alo[64 * 64];
    __shared__ __align__(16) ushort_t Wh[64 * 64];
    __shared__ __align__(16) ushort_t Wl[64 * 64];

    const int tid = threadIdx.x;
    const int lane = tid & 63;
    const int w = tid >> 6;
    const int l15 = lane & 15;
    const int l4 = lane >> 4;
    const int row0 = blockIdx.x * 64;

    f32x4 acc[4] = {};
    float s1p[4] = {}, s2p[4] = {};

    const int srow = tid >> 4;   // 0..15
    const int sc = tid & 15;     // 16-float4 chunks across k=64
    const int wcol = tid >> 2;   // 0..63
    const int wq = tid & 3;

    float4 rA[4];
    s16x8 rWh[2], rWl[2];

    auto loadT = [&](int kt) {
        const int k0 = kt * 64;
#pragma unroll
        for (int p = 0; p < 4; ++p) {
            int grow = row0 + p * 16 + srow;
            rA[p] = make_float4(0.f, 0.f, 0.f, 0.f);
            if (grow < M) rA[p] = *(const float4*)(A + (size_t)grow * SEMD + k0 + sc * 4);
        }
        const ushort_t* sh = WThi + (size_t)wcol * SEMD + k0 + wq * 16;
        const ushort_t* sl = WTlo + (size_t)wcol * SEMD + k0 + wq * 16;
        rWh[0] = *(const s16x8*)sh;
        rWh[1] = *(const s16x8*)(sh + 8);
        rWl[0] = *(const s16x8*)sl;
        rWl[1] = *(const s16x8*)(sl + 8);
    };

    loadT(0);

    for (int kt = 0; kt < 16; ++kt) {
        float4 va1w, va2w;
        if (DOS12) {
            va1w = *(const float4*)(wa1 + kt * 64 + sc * 4);
            va2w = *(const float4*)(wa2 + kt * 64 + sc * 4);
        }
        CFENCE();
        __builtin_amdgcn_s_barrier();   // LDS consumable (prev tile's reads done)
        CFENCE();
        // convert + write LDS (truncation split)
#pragma unroll
        for (int p = 0; p < 4; ++p) {
            float4 v = rA[p];
            if (DOS12) {
                s1p[p] += v.x * va1w.x + v.y * va1w.y + v.z * va1w.z + v.w * va1w.w;
                s2p[p] += v.x * va2w.x + v.y * va2w.y + v.z * va2w.z + v.w * va2w.w;
            }
            unsigned ux = __float_as_uint(v.x), uy = __float_as_uint(v.y);
            unsigned uz = __float_as_uint(v.z), uw = __float_as_uint(v.w);
            ushort4 hv, lv;
            hv.x = (ushort_t)(ux >> 16); hv.y = (ushort_t)(uy >> 16);
            hv.z = (ushort_t)(uz >> 16); hv.w = (ushort_t)(uw >> 16);
            lv.x = (ushort_t)(__float_as_uint(v.x - __uint_as_float(ux & 0xFFFF0000u)) >> 16);
            lv.y = (ushort_t)(__float_as_uint(v.y - __uint_as_float(uy & 0xFFFF0000u)) >> 16);
            lv.z = (ushort_t)(__float_as_uint(v.z - __uint_as_float(uz & 0xFFFF0000u)) >> 16);
            lv.w = (ushort_t)(__float_as_uint(v.w - __uint_as_float(uw & 0xFFFF0000u)) >> 16);
            int rin = p * 16 + srow;
            int boff = rin * 128 + ((sc * 8) ^ ((rin & 7) << 4));
            *(ushort4*)((char*)Ah + boff) = hv;
            *(ushort4*)((char*)Alo + boff) = lv;
        }
        {
            char* dh = (char*)Wh + wcol * 128;
            char* dl = (char*)Wl + wcol * 128;
            int sw = (wcol & 7) << 4;
            *(s16x8*)(dh + ((wq * 32) ^ sw)) = rWh[0];
            *(s16x8*)(dh + ((wq * 32 + 16) ^ sw)) = rWh[1];
            *(s16x8*)(dl + ((wq * 32) ^ sw)) = rWl[0];
            *(s16x8*)(dl + ((wq * 32 + 16) ^ sw)) = rWl[1];
        }
        if (kt < 15) loadT(kt + 1);   // prefetch stays in flight across barrier
        asm volatile("s_waitcnt lgkmcnt(0)" ::: "memory");
        __builtin_amdgcn_s_barrier();
        CFENCE();

        s16x8 fah[2], fal[2];
#pragma unroll
        for (int kf = 0; kf < 2; ++kf) {
            int row = w * 16 + l15;
            int bc = kf * 64 + l4 * 16;
            int off = row * 128 + (bc ^ ((row & 7) << 4));
            fah[kf] = *(const s16x8*)((const char*)Ah + off);
            fal[kf] = *(const s16x8*)((const char*)Alo + off);
        }
#pragma unroll
        for (int cg = 0; cg < 4; ++cg) {
            s16x8 fwh[2], fwl[2];
#pragma unroll
            for (int kf = 0; kf < 2; ++kf) {
                int col = cg * 16 + l15;
                int bc = kf * 64 + l4 * 16;
                int off = col * 128 + (bc ^ ((col & 7) << 4));
                fwh[kf] = *(const s16x8*)((const char*)Wh + off);
                fwl[kf] = *(const s16x8*)((const char*)Wl + off);
            }
#pragma unroll
            for (int kf = 0; kf < 2; ++kf) {
                acc[cg] = __builtin_amdgcn_mfma_f32_16x16x32_bf16(fah[kf], fwh[kf], acc[cg], 0, 0, 0);
                acc[cg] = __builtin_amdgcn_mfma_f32_16x16x32_bf16(fah[kf], fwl[kf], acc[cg], 0, 0, 0);
                acc[cg] = __builtin_amdgcn_mfma_f32_16x16x32_bf16(fal[kf], fwh[kf], acc[cg], 0, 0, 0);
            }
        }
    }

    if (DOS12) {
#pragma unroll
        for (int p = 0; p < 4; ++p) {
            float v1 = s1p[p], v2 = s2p[p];
#pragma unroll
            for (int m = 1; m < 16; m <<= 1) {
                v1 += __shfl_xor(v1, m);
                v2 += __shfl_xor(v2, m);
            }
            int grow = row0 + p * 16 + srow;
            if (sc == 0 && grow < M) {
                s1[grow] = v1;
                s2[grow] = v2;
            }
        }
    }

    // epilogue: D col = cg*16 + l15, row = row0 + w*16 + l4*4 + j
#pragma unroll
    for (int cg = 0; cg < 4; ++cg) {
        int col = cg * 16 + l15;
        float b = bias[col];
#pragma unroll
        for (int j = 0; j < 4; ++j) {
            int grow = row0 + w * 16 + l4 * 4 + j;
            if (grow < M) {
                float x = acc[cg][j] + b;
                float e = x > 0.f ? x : (expf(x) - 1.f);
                float v = (emb[(size_t)grow * DD + col] + e) * 0.5f;
                if (DOS12) out32[(size_t)grow * DD + col] = v;
                out16[(size_t)grow * DD + col] = f2bf(v);
            }
        }
    }
}

// ---------- attention + h' + merge: one wave per item row -> T0 (bf16) ----------
__global__ __launch_bounds__(256) void att_kernel(const int* __restrict__ adj,
                                                  const float* __restrict__ s1,
                                                  const float* __restrict__ s2,
                                                  const float* __restrict__ M0,
                                                  const ushort_t* __restrict__ M0h,
                                                  ushort_t* __restrict__ T0) {
    int gid = blockIdx.x * 256 + threadIdx.x;
    int row = gid >> 6;
    int lane = gid & 63;
    if (row >= NUM_ITEMS) return;
    int kk = lane & 31;
    int col = adj[(size_t)row * KNBR + kk];
    float e = s1[col] + s2[row];
    e = e > 0.f ? e : LALPHA * e;
    float mx = e;
#pragma unroll
    for (int m = 1; m < 32; m <<= 1) mx = fmaxf(mx, __shfl_xor(mx, m));
    float ex = expf(e - mx);
    float ssum = ex;
#pragma unroll
    for (int m = 1; m < 32; m <<= 1) ssum += __shfl_xor(ssum, m);
    float wgt = ex / ssum;
    float h = 0.f;
#pragma unroll
    for (int k = 0; k < 32; ++k) {
        int ck = __builtin_amdgcn_readlane(col, k);
        float wk = __uint_as_float((unsigned)__builtin_amdgcn_readlane(
            (int)__float_as_uint(wgt), k));
        h += wk * bf2f(M0h[(size_t)ck * DD + lane]);
    }
    float eh = h > 0.f ? h : (expf(h) - 1.f);
    float v = (M0[(size_t)row * DD + lane] + eh) * 0.5f;
    T0[(size_t)(NUM_USERS + row) * DD + lane] = f2bf(v);
}

// ---------- bucket histogram (LDS-aggregated) ----------
__global__ __launch_bounds__(256) void bhist(const int* __restrict__ grows,
                                             int* __restrict__ bcnt) {
    __shared__ int h[NBKT];
    int tid = threadIdx.x;
    int base = blockIdx.x * 4096;
    for (int i = tid; i < NBKT; i += 256) h[i] = 0;
    __syncthreads();
#pragma unroll 4
    for (int j = 0; j < 16; ++j) {
        int e = base + j * 256 + tid;
        if (e < NNZE) atomicAdd(&h[grows[e] >> 7], 1);
    }
    __syncthreads();
    for (int b = tid; b < NBKT; b += 256)
        if (h[b]) atomicAdd(&bcnt[b], h[b]);
}

// ---------- bucket scan: bases for binA + total ----------
__global__ __launch_bounds__(256) void bscan(const int* __restrict__ bcnt,
                                             int* __restrict__ bbase,
                                             int* __restrict__ bcursor,
                                             int* __restrict__ rowptr) {
    __shared__ int part[256];
    int t = threadIdx.x;
    int loc[3];
    int s = 0;
#pragma unroll
    for (int i = 0; i < 3; ++i) {
        int idx = t * 3 + i;
        int v = (idx < NBKT) ? bcnt[idx] : 0;
        loc[i] = v;
        s += v;
    }
    part[t] = s;
    __syncthreads();
    for (int off = 1; off < 256; off <<= 1) {
        int x = (t >= off) ? part[t - off] : 0;
        __syncthreads();
        part[t] += x;
        __syncthreads();
    }
    int excl = t ? part[t - 1] : 0;
#pragma unroll
    for (int i = 0; i < 3; ++i) {
        int idx = t * 3 + i;
        if (idx < NBKT) {
            bbase[idx] = excl;
            bcursor[idx] = excl;
            excl += loc[i];
        }
    }
    if (t == 255) {
        bbase[NBKT] = part[255];
        rowptr[NTOT] = part[255];
    }
}

// ---------- Phase A: bin edges by row>>7, grouped writes ----------
__global__ __launch_bounds__(256) void binA(const int* __restrict__ grows,
                                            const int* __restrict__ gcols,
                                            const float* __restrict__ gvals,
                                            int* __restrict__ bcursor,
                                            int2* __restrict__ temp) {
    __shared__ int hist[NBKT];
    __shared__ int gcur[NBKT];
    int tid = threadIdx.x;
    int base = blockIdx.x * 4096;
    for (int i = tid; i < NBKT; i += 256) hist[i] = 0;
    __syncthreads();
#pragma unroll 4
    for (int j = 0; j < 16; ++j) {
        int e = base + j * 256 + tid;
        if (e < NNZE) atomicAdd(&hist[grows[e] >> 7], 1);
    }
    __syncthreads();
    for (int b = tid; b < NBKT; b += 256) {
        int n = hist[b];
        gcur[b] = n ? atomicAdd(&bcursor[b], n) : 0;
    }
    __syncthreads();
#pragma unroll 4
    for (int j = 0; j < 16; ++j) {
        int e = base + j * 256 + tid;
        if (e < NNZE) {
            int r = grows[e];
            int b = r >> 7;
            int pos = atomicAdd(&gcur[b], 1);
            temp[pos] = make_int2((gcols[e] & 0x1FFFF) | ((r & 127) << 17),
                                  __float_as_int(gvals[e]));
        }
    }
}

// ---------- Phase B: in-LDS bucket sort -> rowptr + CSR-ordered sedge (coalesced) ----------
__global__ __launch_bounds__(256) void binB2(const int* __restrict__ bbase,
                                             int2* __restrict__ sedge,
                                             int* __restrict__ rowptr) {
    __shared__ int2 ebuf[BCAP];
    __shared__ int2 obuf[BCAP];
    __shared__ int rc[128];
    __shared__ int ro[128];
    int b = blockIdx.x;
    int tid = threadIdx.x;
    int base = bbase[b];
    int n = min(bbase[b + 1] - base, BCAP);
    for (int i = tid; i < n; i += 256) ebuf[i] = sedge[base + i];
    if (tid < 128) rc[tid] = 0;
    __syncthreads();
    for (int i = tid; i < n; i += 256)
        atomicAdd(&rc[(ebuf[i].x >> 17) & 127], 1);
    __syncthreads();
    if (tid < 128) ro[tid] = rc[tid];
    __syncthreads();
    for (int off = 1; off < 128; off <<= 1) {
        int x = (tid < 128 && tid >= off) ? ro[tid - off] : 0;
        __syncthreads();
        if (tid < 128) ro[tid] += x;
        __syncthreads();
    }
    if (tid < 128) {
        int excl = ro[tid] - rc[tid];
        int gr = (b << 7) + tid;
        if (gr < NTOT) rowptr[gr] = base + excl;
        rc[tid] = excl;   // reuse as within-bucket cursor
    }
    __syncthreads();
    for (int i = tid; i < n; i += 256) {
        int2 w = ebuf[i];
        int r = (w.x >> 17) & 127;
        int pos = atomicAdd(&rc[r], 1);
        obuf[pos] = make_int2(w.x & 0x1FFFF, w.y);
    }
    __syncthreads();
    for (int i = tid; i < n; i += 256) sedge[base + i] = obuf[i];
}

// ---------- SpMM layer (pull, scalar edge loads): one wave per row ----------
__global__ __launch_bounds__(256) void spmm16(const int* __restrict__ rowptr,
                                              const int2* __restrict__ sedge,
                                              const ushort_t* __restrict__ cur,
                                              ushort_t* __restrict__ nxt) {
    int row = __builtin_amdgcn_readfirstlane((blockIdx.x * 256 + threadIdx.x) >> 6);
    int lane = threadIdx.x & 63;
    if (row >= NTOT) return;
    int i = rowptr[row];
    int e = rowptr[row + 1];
    float acc = 0.f;
    for (; i + 4 <= e; i += 4) {
        int2 ed0 = sedge[i];
        int2 ed1 = sedge[i + 1];
        int2 ed2 = sedge[i + 2];
        int2 ed3 = sedge[i + 3];
        float x0 = bf2f(cur[(size_t)ed0.x * DD + lane]);
        float x1 = bf2f(cur[(size_t)ed1.x * DD + lane]);
        float x2 = bf2f(cur[(size_t)ed2.x * DD + lane]);
        float x3 = bf2f(cur[(size_t)ed3.x * DD + lane]);
        acc += __int_as_float(ed0.y) * x0;
        acc += __int_as_float(ed1.y) * x1;
        acc += __int_as_float(ed2.y) * x2;
        acc += __int_as_float(ed3.y) * x3;
    }
    for (; i < e; ++i) {
        int2 ed = sedge[i];
        acc += __int_as_float(ed.y) * bf2f(cur[(size_t)ed.x * DD + lane]);
    }
    nxt[(size_t)row * DD + lane] = f2bf(acc);
}

// ---------- final: sum 4 layer tables at gathered rows, dot, /16 ----------
__global__ __launch_bounds__(256) void gamma_kernel(const int* __restrict__ users,
                                                    const int* __restrict__ items,
                                                    const ushort_t* __restrict__ T0,
                                                    const ushort_t* __restrict__ T1,
                                                    const ushort_t* __restrict__ T2,
                                                    const ushort_t* __restrict__ T3,
                                                    float* __restrict__ out) {
    int gid = blockIdx.x * 256 + threadIdx.x;
    int b = gid >> 6;
    int lane = gid & 63;
    if (b >= BBATCH) return;
    size_t ou = (size_t)users[b] * DD + lane;
    size_t oi = (size_t)(NUM_USERS + items[b]) * DD + lane;
    float su = bf2f(T0[ou]) + bf2f(T1[ou]) + bf2f(T2[ou]) + bf2f(T3[ou]);
    float si = bf2f(T0[oi]) + bf2f(T1[oi]) + bf2f(T2[oi]) + bf2f(T3[oi]);
    float p = su * si;
#pragma unroll
    for (int m = 32; m; m >>= 1) p += __shfl_xor(p, m);
    if (lane == 0) out[b] = p * 0.0625f;
}

extern "C" void kernel_launch(void* const* d_in, const int* in_sizes, int n_in,
                              void* d_out, int out_size, void* d_ws, size_t ws_size,
                              hipStream_t stream) {
    const int* users = (const int*)d_in[0];
    const int* items = (const int*)d_in[1];
    const int* adj = (const int*)d_in[2];
    const int* grows = (const int*)d_in[3];
    const int* gcols = (const int*)d_in[4];
    const float* gvals = (const float*)d_in[5];
    const float* sem = (const float*)d_in[6];
    const float* usem = (const float*)d_in[7];
    const float* emb_user = (const float*)d_in[8];
    const float* emb_item = (const float*)d_in[9];
    const float* W_sem = (const float*)d_in[10];
    const float* b_sem = (const float*)d_in[11];
    const float* W_usem = (const float*)d_in[12];
    const float* b_usem = (const float*)d_in[13];
    const float* W_att = (const float*)d_in[14];
    const float* a_att = (const float*)d_in[15];
    float* out = (float*)d_out;

    const size_t NE = (size_t)NTOT * DD;          // 5.76M
    const size_t IE = (size_t)NUM_ITEMS * DD;     // 1.92M
    char* p = (char*)d_ws;
    ushort_t* T0 = (ushort_t*)p;    p += NE * 2;
    ushort_t* T1 = (ushort_t*)p;    p += NE * 2;
    ushort_t* T2 = (ushort_t*)p;    p += NE * 2;
    ushort_t* T3 = (ushort_t*)p;    p += NE * 2;
    float* M0 = (float*)p;          p += IE * 4;
    ushort_t* M0h = (ushort_t*)p;   p += IE * 2;
    int2* sedge = (int2*)p;         p += (size_t)NNZE * 8;
    ushort_t* WThiU = (ushort_t*)p; p += 65536 * 2;
    ushort_t* WTloU = (ushort_t*)p; p += 65536 * 2;
    ushort_t* WThiS = (ushort_t*)p; p += 65536 * 2;
    ushort_t* WTloS = (ushort_t*)p; p += 65536 * 2;
    float* s1 = (float*)p;          p += NUM_ITEMS * 4;
    float* s2 = (float*)p;          p += NUM_ITEMS * 4;
    float* wa1 = (float*)p;         p += SEMD * 4;
    float* wa2 = (float*)p;         p += SEMD * 4;
    int* rowptr = (int*)p;          p += (NTOT + 4) * 4;
    int* bcnt = (int*)p;            p += NBKT * 4;
    int* bbase = (int*)p;           p += (NBKT + 1) * 4;
    int* bcursor = (int*)p;         p += NBKT * 4;

    hipMemsetAsync(bcnt, 0, NBKT * sizeof(int), stream);
    wsplit<<<513, 256, 0, stream>>>(W_usem, W_sem, WThiU, WTloU, WThiS, WTloS,
                                    W_att, a_att, wa1, wa2);

    gemm_mfma<false><<<(NUM_USERS + 63) / 64, 256, 0, stream>>>(
        usem, WThiU, WTloU, b_usem, emb_user, nullptr, T0, NUM_USERS,
        nullptr, nullptr, nullptr, nullptr);
    gemm_mfma<true><<<(NUM_ITEMS + 63) / 64, 256, 0, stream>>>(
        sem, WThiS, WTloS, b_sem, emb_item, M0, M0h, NUM_ITEMS,
        wa1, wa2, s1, s2);

    att_kernel<<<(NUM_ITEMS * 64 + 255) / 256, 256, 0, stream>>>(adj, s1, s2, M0, M0h, T0);

    bhist<<<(NNZE + 4095) / 4096, 256, 0, stream>>>(grows, bcnt);
    bscan<<<1, 256, 0, stream>>>(bcnt, bbase, bcursor, rowptr);
    binA<<<(NNZE + 4095) / 4096, 256, 0, stream>>>(grows, gcols, gvals, bcursor, sedge);
    binB2<<<NBKT, 256, 0, stream>>>(bbase, sedge, rowptr);

    ushort_t* tabs[4] = {T0, T1, T2, T3};
    for (int l = 0; l < NLAYERS; ++l) {
        spmm16<<<(NTOT * 64 + 255) / 256, 256, 0, stream>>>(rowptr, sedge,
                                                            tabs[l], tabs[l + 1]);
    }
    gamma_kernel<<<(BBATCH * 64 + 255) / 256, 256, 0, stream>>>(users, items,
                                                                T0, T1, T2, T3, out);
}

// Round 13
// 402.721 us; speedup vs baseline: 1.6314x; 1.0102x over previous
//
#include <hip/hip_runtime.h>
#include <hip/hip_bf16.h>
#include <math.h>

#define NUM_USERS 60000
#define NUM_ITEMS 30000
#define DD 64
#define SEMD 1024
#define HIDD 32
#define KNBR 32
#define NNZE 2000000
#define NLAYERS 3
#define BBATCH 4096
#define LALPHA 0.2f
#define NTOT (NUM_USERS + NUM_ITEMS)
#define NBKT 704                         // buckets = row>>7
#define BCAP 3328                        // bucket LDS cap (+9 sigma)
#define GBH 489                          // bhist/binA grid ((NNZE+4095)/4096)

typedef unsigned short ushort_t;
typedef short s16x8 __attribute__((ext_vector_type(8)));
typedef float f32x4 __attribute__((ext_vector_type(4)));

__device__ __forceinline__ ushort_t f2bf(float x) {  // RNE
    unsigned u = __float_as_uint(x);
    return (ushort_t)((u + 0x7FFFu + ((u >> 16) & 1u)) >> 16);
}
__device__ __forceinline__ float bf2f(ushort_t s) {
    return __uint_as_float(((unsigned)s) << 16);
}

#define CFENCE() asm volatile("" ::: "memory")

// ---------- fused: bhist (bid<GBH) | wsplit (GBH..GBH+511) | prep_wa (last) ----------
__global__ __launch_bounds__(256) void prep_fused(
    const float* __restrict__ Wu, const float* __restrict__ Ws,
    ushort_t* __restrict__ hiU, ushort_t* __restrict__ loU,
    ushort_t* __restrict__ hiS, ushort_t* __restrict__ loS,
    const float* __restrict__ W_att, const float* __restrict__ a_att,
    float* __restrict__ wa1, float* __restrict__ wa2,
    const int* __restrict__ grows, int* __restrict__ bcnt) {
    __shared__ int h[NBKT];
    int tid = threadIdx.x;
    int bid = blockIdx.x;
    if (bid < GBH) {   // bhist
        int base = bid * 4096;
        for (int i = tid; i < NBKT; i += 256) h[i] = 0;
        __syncthreads();
#pragma unroll 4
        for (int j = 0; j < 16; ++j) {
            int e = base + j * 256 + tid;
            if (e < NNZE) atomicAdd(&h[grows[e] >> 7], 1);
        }
        __syncthreads();
        for (int b = tid; b < NBKT; b += 256)
            if (h[b]) atomicAdd(&bcnt[b], h[b]);
        return;
    }
    if (bid == GBH + 512) {   // prep_wa
#pragma unroll
        for (int r = 0; r < 4; ++r) {
            int k = tid * 4 + r;
            float d1 = 0.f, d2 = 0.f;
#pragma unroll
            for (int hh = 0; hh < HIDD; ++hh) {
                float w = W_att[k * HIDD + hh];
                d1 += w * a_att[hh];
                d2 += w * a_att[HIDD + hh];
            }
            wa1[k] = d1;
            wa2[k] = d2;
        }
        return;
    }
    // wsplit
    int id = (bid - GBH) * 256 + tid;  // 0..131071
    int i = id & 65535;
    int k = i & 1023;
    int c = i >> 10;
    float x = (id < 65536) ? Wu[(size_t)k * DD + c] : Ws[(size_t)k * DD + c];
    ushort_t hh = f2bf(x);
    ushort_t ll = f2bf(x - bf2f(hh));
    ushort_t* dh = (id < 65536) ? hiU : hiS;
    ushort_t* dl = (id < 65536) ? loU : loS;
    dh[(size_t)c * SEMD + k] = hh;
    dl[(size_t)c * SEMD + k] = ll;
}

// ---------- MFMA bf16x3 GEMM: R5 structure + 2-deep A register pipeline ----------
// BM=64, BK=64, 256 threads (4 waves), each wave 16 rows x 64 cols.
#define LOAD_A(KT, RA)                                                          \
    _Pragma("unroll")                                                           \
    for (int p = 0; p < 4; ++p) {                                               \
        int grow_ = row0 + p * 16 + srow;                                       \
        RA[p] = make_float4(0.f, 0.f, 0.f, 0.f);                                \
        if (grow_ < M)                                                          \
            RA[p] = *(const float4*)(A + (size_t)grow_ * SEMD + (KT) * 64 + sc * 4); \
    }

#define LOAD_W(KT)                                                              \
    {                                                                           \
        const ushort_t* sh_ = WThi + (size_t)wcol * SEMD + (KT) * 64 + wq * 16; \
        const ushort_t* sl_ = WTlo + (size_t)wcol * SEMD + (KT) * 64 + wq * 16; \
        rWh[0] = *(const s16x8*)sh_;                                            \
        rWh[1] = *(const s16x8*)(sh_ + 8);                                      \
        rWl[0] = *(const s16x8*)sl_;                                            \
        rWl[1] = *(const s16x8*)(sl_ + 8);                                      \
    }

#define GEMM_STEP(KT, RA)                                                       \
    {                                                                           \
        float4 va1w, va2w;                                                      \
        if (DOS12) {                                                            \
            va1w = *(const float4*)(wa1 + (KT) * 64 + sc * 4);                  \
            va2w = *(const float4*)(wa2 + (KT) * 64 + sc * 4);                  \
        }                                                                       \
        CFENCE();                                                               \
        __builtin_amdgcn_s_barrier();                                           \
        CFENCE();                                                               \
        _Pragma("unroll")                                                       \
        for (int p = 0; p < 4; ++p) {                                           \
            float4 v = RA[p];                                                   \
            if (DOS12) {                                                        \
                s1p[p] += v.x * va1w.x + v.y * va1w.y + v.z * va1w.z + v.w * va1w.w; \
                s2p[p] += v.x * va2w.x + v.y * va2w.y + v.z * va2w.z + v.w * va2w.w; \
            }                                                                   \
            unsigned ux = __float_as_uint(v.x), uy = __float_as_uint(v.y);      \
            unsigned uz = __float_as_uint(v.z), uw = __float_as_uint(v.w);      \
            ushort4 hv, lv;                                                     \
            hv.x = (ushort_t)(ux >> 16); hv.y = (ushort_t)(uy >> 16);           \
            hv.z = (ushort_t)(uz >> 16); hv.w = (ushort_t)(uw >> 16);           \
            lv.x = (ushort_t)(__float_as_uint(v.x - __uint_as_float(ux & 0xFFFF0000u)) >> 16); \
            lv.y = (ushort_t)(__float_as_uint(v.y - __uint_as_float(uy & 0xFFFF0000u)) >> 16); \
            lv.z = (ushort_t)(__float_as_uint(v.z - __uint_as_float(uz & 0xFFFF0000u)) >> 16); \
            lv.w = (ushort_t)(__float_as_uint(v.w - __uint_as_float(uw & 0xFFFF0000u)) >> 16); \
            int rin_ = p * 16 + srow;                                           \
            int boff_ = rin_ * 128 + ((sc * 8) ^ ((rin_ & 7) << 4));            \
            *(ushort4*)((char*)Ah + boff_) = hv;                                \
            *(ushort4*)((char*)Alo + boff_) = lv;                               \
        }                                                                       \
        {                                                                       \
            char* dh_ = (char*)Wh + wcol * 128;                                 \
            char* dl_ = (char*)Wl + wcol * 128;                                 \
            int sw_ = (wcol & 7) << 4;                                          \
            *(s16x8*)(dh_ + ((wq * 32) ^ sw_)) = rWh[0];                        \
            *(s16x8*)(dh_ + ((wq * 32 + 16) ^ sw_)) = rWh[1];                   \
            *(s16x8*)(dl_ + ((wq * 32) ^ sw_)) = rWl[0];                        \
            *(s16x8*)(dl_ + ((wq * 32 + 16) ^ sw_)) = rWl[1];                   \
        }                                                                       \
        if ((KT) + 2 < 16) { LOAD_A((KT) + 2, RA) }                             \
        if ((KT) + 1 < 16) { LOAD_W((KT) + 1) }                                 \
        asm volatile("s_waitcnt lgkmcnt(0)" ::: "memory");                      \
        __builtin_amdgcn_s_barrier();                                           \
        CFENCE();                                                               \
        s16x8 fah[2], fal[2];                                                   \
        _Pragma("unroll")                                                       \
        for (int kf = 0; kf < 2; ++kf) {                                        \
            int row_ = w * 16 + l15;                                            \
            int bc_ = kf * 64 + l4 * 16;                                        \
            int off_ = row_ * 128 + (bc_ ^ ((row_ & 7) << 4));                  \
            fah[kf] = *(const s16x8*)((const char*)Ah + off_);                  \
            fal[kf] = *(const s16x8*)((const char*)Alo + off_);                 \
        }                                                                       \
        _Pragma("unroll")                                                       \
        for (int cg = 0; cg < 4; ++cg) {                                        \
            s16x8 fwh[2], fwl[2];                                               \
            _Pragma("unroll")                                                   \
            for (int kf = 0; kf < 2; ++kf) {                                    \
                int col_ = cg * 16 + l15;                                       \
                int bc_ = kf * 64 + l4 * 16;                                    \
                int off_ = col_ * 128 + (bc_ ^ ((col_ & 7) << 4));              \
                fwh[kf] = *(const s16x8*)((const char*)Wh + off_);              \
                fwl[kf] = *(const s16x8*)((const char*)Wl + off_);              \
            }                                                                   \
            _Pragma("unroll")                                                   \
            for (int kf = 0; kf < 2; ++kf) {                                    \
                acc[cg] = __builtin_amdgcn_mfma_f32_16x16x32_bf16(fah[kf], fwh[kf], acc[cg], 0, 0, 0); \
                acc[cg] = __builtin_amdgcn_mfma_f32_16x16x32_bf16(fah[kf], fwl[kf], acc[cg], 0, 0, 0); \
                acc[cg] = __builtin_amdgcn_mfma_f32_16x16x32_bf16(fal[kf], fwh[kf], acc[cg], 0, 0, 0); \
            }                                                                   \
        }                                                                       \
    }

template <bool DOS12>
__global__ __launch_bounds__(256) void gemm_mfma(
    const float* __restrict__ A,
    const ushort_t* __restrict__ WThi,
    const ushort_t* __restrict__ WTlo,
    const float* __restrict__ bias,
    const float* __restrict__ emb,
    float* __restrict__ out32,       // only written when DOS12 (items: M0)
    ushort_t* __restrict__ out16,
    int M,
    const float* __restrict__ wa1,
    const float* __restrict__ wa2,
    float* __restrict__ s1,
    float* __restrict__ s2) {
    __shared__ __align__(16) ushort_t Ah[64 * 64];
    __shared__ __align__(16) ushort_t Alo[64 * 64];
    __shared__ __align__(16) ushort_t Wh[64 * 64];
    __shared__ __align__(16) ushort_t Wl[64 * 64];

    const int tid = threadIdx.x;
    const int lane = tid & 63;
    const int w = tid >> 6;
    const int l15 = lane & 15;
    const int l4 = lane >> 4;
    const int row0 = blockIdx.x * 64;

    f32x4 acc[4] = {};
    float s1p[4] = {}, s2p[4] = {};

    const int srow = tid >> 4;
    const int sc = tid & 15;
    const int wcol = tid >> 2;
    const int wq = tid & 3;

    float4 rA0[4], rA1[4];
    s16x8 rWh[2], rWl[2];

    LOAD_A(0, rA0)
    LOAD_A(1, rA1)
    LOAD_W(0)

    for (int kt = 0; kt < 16; kt += 2) {
        GEMM_STEP(kt, rA0)
        GEMM_STEP(kt + 1, rA1)
    }

    if (DOS12) {
#pragma unroll
        for (int p = 0; p < 4; ++p) {
            float v1 = s1p[p], v2 = s2p[p];
#pragma unroll
            for (int m = 1; m < 16; m <<= 1) {
                v1 += __shfl_xor(v1, m);
                v2 += __shfl_xor(v2, m);
            }
            int grow = row0 + p * 16 + srow;
            if (sc == 0 && grow < M) {
                s1[grow] = v1;
                s2[grow] = v2;
            }
        }
    }

#pragma unroll
    for (int cg = 0; cg < 4; ++cg) {
        int col = cg * 16 + l15;
        float b = bias[col];
#pragma unroll
        for (int j = 0; j < 4; ++j) {
            int grow = row0 + w * 16 + l4 * 4 + j;
            if (grow < M) {
                float x = acc[cg][j] + b;
                float e = x > 0.f ? x : (expf(x) - 1.f);
                float v = (emb[(size_t)grow * DD + col] + e) * 0.5f;
                if (DOS12) out32[(size_t)grow * DD + col] = v;
                out16[(size_t)grow * DD + col] = f2bf(v);
            }
        }
    }
}

// ---------- bucket scan: bases for binA + total ----------
__global__ __launch_bounds__(256) void bscan(const int* __restrict__ bcnt,
                                             int* __restrict__ bbase,
                                             int* __restrict__ bcursor,
                                             int* __restrict__ rowptr) {
    __shared__ int part[256];
    int t = threadIdx.x;
    int loc[3];
    int s = 0;
#pragma unroll
    for (int i = 0; i < 3; ++i) {
        int idx = t * 3 + i;
        int v = (idx < NBKT) ? bcnt[idx] : 0;
        loc[i] = v;
        s += v;
    }
    part[t] = s;
    __syncthreads();
    for (int off = 1; off < 256; off <<= 1) {
        int x = (t >= off) ? part[t - off] : 0;
        __syncthreads();
        part[t] += x;
        __syncthreads();
    }
    int excl = t ? part[t - 1] : 0;
#pragma unroll
    for (int i = 0; i < 3; ++i) {
        int idx = t * 3 + i;
        if (idx < NBKT) {
            bbase[idx] = excl;
            bcursor[idx] = excl;
            excl += loc[i];
        }
    }
    if (t == 255) {
        bbase[NBKT] = part[255];
        rowptr[NTOT] = part[255];
    }
}

// ---------- fused: binA (bid<GBH) | att (rest) ----------
__global__ __launch_bounds__(256) void attbin_fused(
    const int* __restrict__ grows, const int* __restrict__ gcols,
    const float* __restrict__ gvals, int* __restrict__ bcursor,
    int2* __restrict__ sedge,
    const int* __restrict__ adj, const float* __restrict__ s1,
    const float* __restrict__ s2, const float* __restrict__ M0,
    const ushort_t* __restrict__ M0h, ushort_t* __restrict__ T0) {
    __shared__ int hist[NBKT];
    __shared__ int gcur[NBKT];
    int tid = threadIdx.x;
    int bid = blockIdx.x;
    if (bid < GBH) {   // binA
        int base = bid * 4096;
        for (int i = tid; i < NBKT; i += 256) hist[i] = 0;
        __syncthreads();
#pragma unroll 4
        for (int j = 0; j < 16; ++j) {
            int e = base + j * 256 + tid;
            if (e < NNZE) atomicAdd(&hist[grows[e] >> 7], 1);
        }
        __syncthreads();
        for (int b = tid; b < NBKT; b += 256) {
            int n = hist[b];
            gcur[b] = n ? atomicAdd(&bcursor[b], n) : 0;
        }
        __syncthreads();
#pragma unroll 4
        for (int j = 0; j < 16; ++j) {
            int e = base + j * 256 + tid;
            if (e < NNZE) {
                int r = grows[e];
                int b = r >> 7;
                int pos = atomicAdd(&gcur[b], 1);
                sedge[pos] = make_int2((gcols[e] & 0x1FFFF) | ((r & 127) << 17),
                                       __float_as_int(gvals[e]));
            }
        }
        return;
    }
    // att
    int gid = (bid - GBH) * 256 + tid;
    int row = gid >> 6;
    int lane = gid & 63;
    if (row >= NUM_ITEMS) return;
    int kk = lane & 31;
    int col = adj[(size_t)row * KNBR + kk];
    float e = s1[col] + s2[row];
    e = e > 0.f ? e : LALPHA * e;
    float mx = e;
#pragma unroll
    for (int m = 1; m < 32; m <<= 1) mx = fmaxf(mx, __shfl_xor(mx, m));
    float ex = expf(e - mx);
    float ssum = ex;
#pragma unroll
    for (int m = 1; m < 32; m <<= 1) ssum += __shfl_xor(ssum, m);
    float wgt = ex / ssum;
    float h = 0.f;
#pragma unroll
    for (int k = 0; k < 32; ++k) {
        int ck = __builtin_amdgcn_readlane(col, k);
        float wk = __uint_as_float((unsigned)__builtin_amdgcn_readlane(
            (int)__float_as_uint(wgt), k));
        h += wk * bf2f(M0h[(size_t)ck * DD + lane]);
    }
    float eh = h > 0.f ? h : (expf(h) - 1.f);
    float v = (M0[(size_t)row * DD + lane] + eh) * 0.5f;
    T0[(size_t)(NUM_USERS + row) * DD + lane] = f2bf(v);
}

// ---------- Phase B: in-LDS bucket sort -> rowptr + CSR-ordered sedge ----------
__global__ __launch_bounds__(256) void binB2(const int* __restrict__ bbase,
                                             int2* __restrict__ sedge,
                                             int* __restrict__ rowptr) {
    __shared__ int2 ebuf[BCAP];
    __shared__ int2 obuf[BCAP];
    __shared__ int rc[128];
    __shared__ int ro[128];
    int b = blockIdx.x;
    int tid = threadIdx.x;
    int base = bbase[b];
    int n = min(bbase[b + 1] - base, BCAP);
    for (int i = tid; i < n; i += 256) ebuf[i] = sedge[base + i];
    if (tid < 128) rc[tid] = 0;
    __syncthreads();
    for (int i = tid; i < n; i += 256)
        atomicAdd(&rc[(ebuf[i].x >> 17) & 127], 1);
    __syncthreads();
    if (tid < 128) ro[tid] = rc[tid];
    __syncthreads();
    for (int off = 1; off < 128; off <<= 1) {
        int x = (tid < 128 && tid >= off) ? ro[tid - off] : 0;
        __syncthreads();
        if (tid < 128) ro[tid] += x;
        __syncthreads();
    }
    if (tid < 128) {
        int excl = ro[tid] - rc[tid];
        int gr = (b << 7) + tid;
        if (gr < NTOT) rowptr[gr] = base + excl;
        rc[tid] = excl;
    }
    __syncthreads();
    for (int i = tid; i < n; i += 256) {
        int2 w = ebuf[i];
        int r = (w.x >> 17) & 127;
        int pos = atomicAdd(&rc[r], 1);
        obuf[pos] = make_int2(w.x & 0x1FFFF, w.y);
    }
    __syncthreads();
    for (int i = tid; i < n; i += 256) sedge[base + i] = obuf[i];
}

// ---------- SpMM layer (pull, scalar edge loads): one wave per row ----------
__global__ __launch_bounds__(256) void spmm16(const int* __restrict__ rowptr,
                                              const int2* __restrict__ sedge,
                                              const ushort_t* __restrict__ cur,
                                              ushort_t* __restrict__ nxt) {
    int row = __builtin_amdgcn_readfirstlane((blockIdx.x * 256 + threadIdx.x) >> 6);
    int lane = threadIdx.x & 63;
    if (row >= NTOT) return;
    int i = rowptr[row];
    int e = rowptr[row + 1];
    float acc = 0.f;
    for (; i + 4 <= e; i += 4) {
        int2 ed0 = sedge[i];
        int2 ed1 = sedge[i + 1];
        int2 ed2 = sedge[i + 2];
        int2 ed3 = sedge[i + 3];
        float x0 = bf2f(cur[(size_t)ed0.x * DD + lane]);
        float x1 = bf2f(cur[(size_t)ed1.x * DD + lane]);
        float x2 = bf2f(cur[(size_t)ed2.x * DD + lane]);
        float x3 = bf2f(cur[(size_t)ed3.x * DD + lane]);
        acc += __int_as_float(ed0.y) * x0;
        acc += __int_as_float(ed1.y) * x1;
        acc += __int_as_float(ed2.y) * x2;
        acc += __int_as_float(ed3.y) * x3;
    }
    for (; i < e; ++i) {
        int2 ed = sedge[i];
        acc += __int_as_float(ed.y) * bf2f(cur[(size_t)ed.x * DD + lane]);
    }
    nxt[(size_t)row * DD + lane] = f2bf(acc);
}

// ---------- final: sum 4 layer tables at gathered rows, dot, /16 ----------
__global__ __launch_bounds__(256) void gamma_kernel(const int* __restrict__ users,
                                                    const int* __restrict__ items,
                                                    const ushort_t* __restrict__ T0,
                                                    const ushort_t* __restrict__ T1,
                                                    const ushort_t* __restrict__ T2,
                                                    const ushort_t* __restrict__ T3,
                                                    float* __restrict__ out) {
    int gid = blockIdx.x * 256 + threadIdx.x;
    int b = gid >> 6;
    int lane = gid & 63;
    if (b >= BBATCH) return;
    size_t ou = (size_t)users[b] * DD + lane;
    size_t oi = (size_t)(NUM_USERS + items[b]) * DD + lane;
    float su = bf2f(T0[ou]) + bf2f(T1[ou]) + bf2f(T2[ou]) + bf2f(T3[ou]);
    float si = bf2f(T0[oi]) + bf2f(T1[oi]) + bf2f(T2[oi]) + bf2f(T3[oi]);
    float p = su * si;
#pragma unroll
    for (int m = 32; m; m >>= 1) p += __shfl_xor(p, m);
    if (lane == 0) out[b] = p * 0.0625f;
}

extern "C" void kernel_launch(void* const* d_in, const int* in_sizes, int n_in,
                              void* d_out, int out_size, void* d_ws, size_t ws_size,
                              hipStream_t stream) {
    const int* users = (const int*)d_in[0];
    const int* items = (const int*)d_in[1];
    const int* adj = (const int*)d_in[2];
    const int* grows = (const int*)d_in[3];
    const int* gcols = (const int*)d_in[4];
    const float* gvals = (const float*)d_in[5];
    const float* sem = (const float*)d_in[6];
    const float* usem = (const float*)d_in[7];
    const float* emb_user = (const float*)d_in[8];
    const float* emb_item = (const float*)d_in[9];
    const float* W_sem = (const float*)d_in[10];
    const float* b_sem = (const float*)d_in[11];
    const float* W_usem = (const float*)d_in[12];
    const float* b_usem = (const float*)d_in[13];
    const float* W_att = (const float*)d_in[14];
    const float* a_att = (const float*)d_in[15];
    float* out = (float*)d_out;

    const size_t NE = (size_t)NTOT * DD;          // 5.76M
    const size_t IE = (size_t)NUM_ITEMS * DD;     // 1.92M
    char* p = (char*)d_ws;
    ushort_t* T0 = (ushort_t*)p;    p += NE * 2;
    ushort_t* T1 = (ushort_t*)p;    p += NE * 2;
    ushort_t* T2 = (ushort_t*)p;    p += NE * 2;
    ushort_t* T3 = (ushort_t*)p;    p += NE * 2;
    float* M0 = (float*)p;          p += IE * 4;
    ushort_t* M0h = (ushort_t*)p;   p += IE * 2;
    int2* sedge = (int2*)p;         p += (size_t)NNZE * 8;
    ushort_t* WThiU = (ushort_t*)p; p += 65536 * 2;
    ushort_t* WTloU = (ushort_t*)p; p += 65536 * 2;
    ushort_t* WThiS = (ushort_t*)p; p += 65536 * 2;
    ushort_t* WTloS = (ushort_t*)p; p += 65536 * 2;
    float* s1 = (float*)p;          p += NUM_ITEMS * 4;
    float* s2 = (float*)p;          p += NUM_ITEMS * 4;
    float* wa1 = (float*)p;         p += SEMD * 4;
    float* wa2 = (float*)p;         p += SEMD * 4;
    int* rowptr = (int*)p;          p += (NTOT + 4) * 4;
    int* bcnt = (int*)p;            p += NBKT * 4;
    int* bbase = (int*)p;           p += (NBKT + 1) * 4;
    int* bcursor = (int*)p;         p += NBKT * 4;

    hipMemsetAsync(bcnt, 0, NBKT * sizeof(int), stream);
    prep_fused<<<GBH + 513, 256, 0, stream>>>(W_usem, W_sem, WThiU, WTloU, WThiS, WTloS,
                                              W_att, a_att, wa1, wa2, grows, bcnt);

    gemm_mfma<false><<<(NUM_USERS + 63) / 64, 256, 0, stream>>>(
        usem, WThiU, WTloU, b_usem, emb_user, nullptr, T0, NUM_USERS,
        nullptr, nullptr, nullptr, nullptr);
    gemm_mfma<true><<<(NUM_ITEMS + 63) / 64, 256, 0, stream>>>(
        sem, WThiS, WTloS, b_sem, emb_item, M0, M0h, NUM_ITEMS,
        wa1, wa2, s1, s2);

    bscan<<<1, 256, 0, stream>>>(bcnt, bbase, bcursor, rowptr);
    attbin_fused<<<GBH + (NUM_ITEMS * 64 + 255) / 256, 256, 0, stream>>>(
        grows, gcols, gvals, bcursor, sedge, adj, s1, s2, M0, M0h, T0);
    binB2<<<NBKT, 256, 0, stream>>>(bbase, sedge, rowptr);

    ushort_t* tabs[4] = {T0, T1, T2, T3};
    for (int l = 0; l < NLAYERS; ++l) {
        spmm16<<<(NTOT * 64 + 255) / 256, 256, 0, stream>>>(rowptr, sedge,
                                                            tabs[l], tabs[l + 1]);
    }
    gamma_kernel<<<(BBATCH * 64 + 255) / 256, 256, 0, stream>>>(users, items,
                                                                T0, T1, T2, T3, out);
}

// Round 15
// 354.952 us; speedup vs baseline: 1.8510x; 1.1346x over previous
//
#include <hip/hip_runtime.h>
#include <hip/hip_bf16.h>
#include <math.h>

#define NUM_USERS 60000
#define NUM_ITEMS 30000
#define DD 64
#define SEMD 1024
#define HIDD 32
#define KNBR 32
#define NNZE 2000000
#define NLAYERS 3
#define BBATCH 4096
#define LALPHA 0.2f
#define NTOT (NUM_USERS + NUM_ITEMS)
#define NBKT 704                         // buckets = row>>7
#define BCAP 3328                        // bucket LDS cap (+9 sigma)
#define GBH 489                          // bhist/binA grid ((NNZE+4095)/4096)

typedef unsigned short ushort_t;
typedef short s16x8 __attribute__((ext_vector_type(8)));
typedef float f32x4 __attribute__((ext_vector_type(4)));

__device__ __forceinline__ ushort_t f2bf(float x) {  // RNE
    unsigned u = __float_as_uint(x);
    return (ushort_t)((u + 0x7FFFu + ((u >> 16) & 1u)) >> 16);
}
__device__ __forceinline__ float bf2f(ushort_t s) {
    return __uint_as_float(((unsigned)s) << 16);
}

#define CFENCE() asm volatile("" ::: "memory")

// ---------- fused: bhist (bid<GBH) | wsplit (GBH..GBH+511) | prep_wa (last) ----------
__global__ __launch_bounds__(256) void prep_fused(
    const float* __restrict__ Wu, const float* __restrict__ Ws,
    ushort_t* __restrict__ hiU, ushort_t* __restrict__ loU,
    ushort_t* __restrict__ hiS, ushort_t* __restrict__ loS,
    const float* __restrict__ W_att, const float* __restrict__ a_att,
    float* __restrict__ wa1, float* __restrict__ wa2,
    const int* __restrict__ grows, int* __restrict__ bcnt) {
    __shared__ int h[NBKT];
    int tid = threadIdx.x;
    int bid = blockIdx.x;
    if (bid < GBH) {   // bhist
        int base = bid * 4096;
        for (int i = tid; i < NBKT; i += 256) h[i] = 0;
        __syncthreads();
#pragma unroll 4
        for (int j = 0; j < 16; ++j) {
            int e = base + j * 256 + tid;
            if (e < NNZE) atomicAdd(&h[grows[e] >> 7], 1);
        }
        __syncthreads();
        for (int b = tid; b < NBKT; b += 256)
            if (h[b]) atomicAdd(&bcnt[b], h[b]);
        return;
    }
    if (bid == GBH + 512) {   // prep_wa
#pragma unroll
        for (int r = 0; r < 4; ++r) {
            int k = tid * 4 + r;
            float d1 = 0.f, d2 = 0.f;
#pragma unroll
            for (int hh = 0; hh < HIDD; ++hh) {
                float w = W_att[k * HIDD + hh];
                d1 += w * a_att[hh];
                d2 += w * a_att[HIDD + hh];
            }
            wa1[k] = d1;
            wa2[k] = d2;
        }
        return;
    }
    // wsplit
    int id = (bid - GBH) * 256 + tid;  // 0..131071
    int i = id & 65535;
    int k = i & 1023;
    int c = i >> 10;
    float x = (id < 65536) ? Wu[(size_t)k * DD + c] : Ws[(size_t)k * DD + c];
    ushort_t hh = f2bf(x);
    ushort_t ll = f2bf(x - bf2f(hh));
    ushort_t* dh = (id < 65536) ? hiU : hiS;
    ushort_t* dl = (id < 65536) ? loU : loS;
    dh[(size_t)c * SEMD + k] = hh;
    dl[(size_t)c * SEMD + k] = ll;
}

// ---------- MFMA bf16x3 GEMM: R5 structure + 2-deep A register pipeline ----------
#define LOAD_A(KT, RA)                                                          \
    _Pragma("unroll")                                                           \
    for (int p = 0; p < 4; ++p) {                                               \
        int grow_ = row0 + p * 16 + srow;                                       \
        RA[p] = make_float4(0.f, 0.f, 0.f, 0.f);                                \
        if (grow_ < M)                                                          \
            RA[p] = *(const float4*)(A + (size_t)grow_ * SEMD + (KT) * 64 + sc * 4); \
    }

#define LOAD_W(KT)                                                              \
    {                                                                           \
        const ushort_t* sh_ = WThi + (size_t)wcol * SEMD + (KT) * 64 + wq * 16; \
        const ushort_t* sl_ = WTlo + (size_t)wcol * SEMD + (KT) * 64 + wq * 16; \
        rWh[0] = *(const s16x8*)sh_;                                            \
        rWh[1] = *(const s16x8*)(sh_ + 8);                                      \
        rWl[0] = *(const s16x8*)sl_;                                            \
        rWl[1] = *(const s16x8*)(sl_ + 8);                                      \
    }

#define GEMM_STEP(KT, RA)                                                       \
    {                                                                           \
        float4 va1w, va2w;                                                      \
        if (DOS12) {                                                            \
            va1w = *(const float4*)(wa1 + (KT) * 64 + sc * 4);                  \
            va2w = *(const float4*)(wa2 + (KT) * 64 + sc * 4);                  \
        }                                                                       \
        CFENCE();                                                               \
        __builtin_amdgcn_s_barrier();                                           \
        CFENCE();                                                               \
        _Pragma("unroll")                                                       \
        for (int p = 0; p < 4; ++p) {                                           \
            float4 v = RA[p];                                                   \
            if (DOS12) {                                                        \
                s1p[p] += v.x * va1w.x + v.y * va1w.y + v.z * va1w.z + v.w * va1w.w; \
                s2p[p] += v.x * va2w.x + v.y * va2w.y + v.z * va2w.z + v.w * va2w.w; \
            }                                                                   \
            unsigned ux = __float_as_uint(v.x), uy = __float_as_uint(v.y);      \
            unsigned uz = __float_as_uint(v.z), uw = __float_as_uint(v.w);      \
            ushort4 hv, lv;                                                     \
            hv.x = (ushort_t)(ux >> 16); hv.y = (ushort_t)(uy >> 16);           \
            hv.z = (ushort_t)(uz >> 16); hv.w = (ushort_t)(uw >> 16);           \
            lv.x = (ushort_t)(__float_as_uint(v.x - __uint_as_float(ux & 0xFFFF0000u)) >> 16); \
            lv.y = (ushort_t)(__float_as_uint(v.y - __uint_as_float(uy & 0xFFFF0000u)) >> 16); \
            lv.z = (ushort_t)(__float_as_uint(v.z - __uint_as_float(uz & 0xFFFF0000u)) >> 16); \
            lv.w = (ushort_t)(__float_as_uint(v.w - __uint_as_float(uw & 0xFFFF0000u)) >> 16); \
            int rin_ = p * 16 + srow;                                           \
            int boff_ = rin_ * 128 + ((sc * 8) ^ ((rin_ & 7) << 4));            \
            *(ushort4*)((char*)Ah + boff_) = hv;                                \
            *(ushort4*)((char*)Alo + boff_) = lv;                               \
        }                                                                       \
        {                                                                       \
            char* dh_ = (char*)Wh + wcol * 128;                                 \
            char* dl_ = (char*)Wl + wcol * 128;                                 \
            int sw_ = (wcol & 7) << 4;                                          \
            *(s16x8*)(dh_ + ((wq * 32) ^ sw_)) = rWh[0];                        \
            *(s16x8*)(dh_ + ((wq * 32 + 16) ^ sw_)) = rWh[1];                   \
            *(s16x8*)(dl_ + ((wq * 32) ^ sw_)) = rWl[0];                        \
            *(s16x8*)(dl_ + ((wq * 32 + 16) ^ sw_)) = rWl[1];                   \
        }                                                                       \
        if ((KT) + 2 < 16) { LOAD_A((KT) + 2, RA) }                             \
        if ((KT) + 1 < 16) { LOAD_W((KT) + 1) }                                 \
        asm volatile("s_waitcnt lgkmcnt(0)" ::: "memory");                      \
        __builtin_amdgcn_s_barrier();                                           \
        CFENCE();                                                               \
        s16x8 fah[2], fal[2];                                                   \
        _Pragma("unroll")                                                       \
        for (int kf = 0; kf < 2; ++kf) {                                        \
            int row_ = w * 16 + l15;                                            \
            int bc_ = kf * 64 + l4 * 16;                                        \
            int off_ = row_ * 128 + (bc_ ^ ((row_ & 7) << 4));                  \
            fah[kf] = *(const s16x8*)((const char*)Ah + off_);                  \
            fal[kf] = *(const s16x8*)((const char*)Alo + off_);                 \
        }                                                                       \
        _Pragma("unroll")                                                       \
        for (int cg = 0; cg < 4; ++cg) {                                        \
            s16x8 fwh[2], fwl[2];                                               \
            _Pragma("unroll")                                                   \
            for (int kf = 0; kf < 2; ++kf) {                                    \
                int col_ = cg * 16 + l15;                                       \
                int bc_ = kf * 64 + l4 * 16;                                    \
                int off_ = col_ * 128 + (bc_ ^ ((col_ & 7) << 4));              \
                fwh[kf] = *(const s16x8*)((const char*)Wh + off_);              \
                fwl[kf] = *(const s16x8*)((const char*)Wl + off_);              \
            }                                                                   \
            _Pragma("unroll")                                                   \
            for (int kf = 0; kf < 2; ++kf) {                                    \
                acc[cg] = __builtin_amdgcn_mfma_f32_16x16x32_bf16(fah[kf], fwh[kf], acc[cg], 0, 0, 0); \
                acc[cg] = __builtin_amdgcn_mfma_f32_16x16x32_bf16(fah[kf], fwl[kf], acc[cg], 0, 0, 0); \
                acc[cg] = __builtin_amdgcn_mfma_f32_16x16x32_bf16(fal[kf], fwh[kf], acc[cg], 0, 0, 0); \
            }                                                                   \
        }                                                                       \
    }

template <bool DOS12>
__global__ __launch_bounds__(256) void gemm_mfma(
    const float* __restrict__ A,
    const ushort_t* __restrict__ WThi,
    const ushort_t* __restrict__ WTlo,
    const float* __restrict__ bias,
    const float* __restrict__ emb,
    float* __restrict__ out32,       // only written when DOS12 (items: M0)
    ushort_t* __restrict__ out16,
    int M,
    const float* __restrict__ wa1,
    const float* __restrict__ wa2,
    float* __restrict__ s1,
    float* __restrict__ s2) {
    __shared__ __align__(16) ushort_t Ah[64 * 64];
    __shared__ __align__(16) ushort_t Alo[64 * 64];
    __shared__ __align__(16) ushort_t Wh[64 * 64];
    __shared__ __align__(16) ushort_t Wl[64 * 64];

    const int tid = threadIdx.x;
    const int lane = tid & 63;
    const int w = tid >> 6;
    const int l15 = lane & 15;
    const int l4 = lane >> 4;
    const int row0 = blockIdx.x * 64;

    f32x4 acc[4] = {};
    float s1p[4] = {}, s2p[4] = {};

    const int srow = tid >> 4;
    const int sc = tid & 15;
    const int wcol = tid >> 2;
    const int wq = tid & 3;

    float4 rA0[4], rA1[4];
    s16x8 rWh[2], rWl[2];

    LOAD_A(0, rA0)
    LOAD_A(1, rA1)
    LOAD_W(0)

    for (int kt = 0; kt < 16; kt += 2) {
        GEMM_STEP(kt, rA0)
        GEMM_STEP(kt + 1, rA1)
    }

    if (DOS12) {
#pragma unroll
        for (int p = 0; p < 4; ++p) {
            float v1 = s1p[p], v2 = s2p[p];
#pragma unroll
            for (int m = 1; m < 16; m <<= 1) {
                v1 += __shfl_xor(v1, m);
                v2 += __shfl_xor(v2, m);
            }
            int grow = row0 + p * 16 + srow;
            if (sc == 0 && grow < M) {
                s1[grow] = v1;
                s2[grow] = v2;
            }
        }
    }

#pragma unroll
    for (int cg = 0; cg < 4; ++cg) {
        int col = cg * 16 + l15;
        float b = bias[col];
#pragma unroll
        for (int j = 0; j < 4; ++j) {
            int grow = row0 + w * 16 + l4 * 4 + j;
            if (grow < M) {
                float x = acc[cg][j] + b;
                float e = x > 0.f ? x : (expf(x) - 1.f);
                float v = (emb[(size_t)grow * DD + col] + e) * 0.5f;
                if (DOS12) out32[(size_t)grow * DD + col] = v;
                out16[(size_t)grow * DD + col] = f2bf(v);
            }
        }
    }
}

// ---------- bucket scan: bases for binA + total ----------
__global__ __launch_bounds__(256) void bscan(const int* __restrict__ bcnt,
                                             int* __restrict__ bbase,
                                             int* __restrict__ bcursor,
                                             int* __restrict__ rowptr) {
    __shared__ int part[256];
    int t = threadIdx.x;
    int loc[3];
    int s = 0;
#pragma unroll
    for (int i = 0; i < 3; ++i) {
        int idx = t * 3 + i;
        int v = (idx < NBKT) ? bcnt[idx] : 0;
        loc[i] = v;
        s += v;
    }
    part[t] = s;
    __syncthreads();
    for (int off = 1; off < 256; off <<= 1) {
        int x = (t >= off) ? part[t - off] : 0;
        __syncthreads();
        part[t] += x;
        __syncthreads();
    }
    int excl = t ? part[t - 1] : 0;
#pragma unroll
    for (int i = 0; i < 3; ++i) {
        int idx = t * 3 + i;
        if (idx < NBKT) {
            bbase[idx] = excl;
            bcursor[idx] = excl;
            excl += loc[i];
        }
    }
    if (t == 255) {
        bbase[NBKT] = part[255];
        rowptr[NTOT] = part[255];
    }
}

// ---------- fused: binA (bid<GBH) | att (rest) ----------
__global__ __launch_bounds__(256) void attbin_fused(
    const int* __restrict__ grows, const int* __restrict__ gcols,
    const float* __restrict__ gvals, int* __restrict__ bcursor,
    int2* __restrict__ sedge,
    const int* __restrict__ adj, const float* __restrict__ s1,
    const float* __restrict__ s2, const float* __restrict__ M0,
    const ushort_t* __restrict__ M0h, ushort_t* __restrict__ T0) {
    __shared__ int hist[NBKT];
    __shared__ int gcur[NBKT];
    int tid = threadIdx.x;
    int bid = blockIdx.x;
    if (bid < GBH) {   // binA
        int base = bid * 4096;
        for (int i = tid; i < NBKT; i += 256) hist[i] = 0;
        __syncthreads();
#pragma unroll 4
        for (int j = 0; j < 16; ++j) {
            int e = base + j * 256 + tid;
            if (e < NNZE) atomicAdd(&hist[grows[e] >> 7], 1);
        }
        __syncthreads();
        for (int b = tid; b < NBKT; b += 256) {
            int n = hist[b];
            gcur[b] = n ? atomicAdd(&bcursor[b], n) : 0;
        }
        __syncthreads();
#pragma unroll 4
        for (int j = 0; j < 16; ++j) {
            int e = base + j * 256 + tid;
            if (e < NNZE) {
                int r = grows[e];
                int b = r >> 7;
                int pos = atomicAdd(&gcur[b], 1);
                sedge[pos] = make_int2((gcols[e] & 0x1FFFF) | ((r & 127) << 17),
                                       __float_as_int(gvals[e]));
            }
        }
        return;
    }
    // att
    int gid = (bid - GBH) * 256 + tid;
    int row = gid >> 6;
    int lane = gid & 63;
    if (row >= NUM_ITEMS) return;
    int kk = lane & 31;
    int col = adj[(size_t)row * KNBR + kk];
    float e = s1[col] + s2[row];
    e = e > 0.f ? e : LALPHA * e;
    float mx = e;
#pragma unroll
    for (int m = 1; m < 32; m <<= 1) mx = fmaxf(mx, __shfl_xor(mx, m));
    float ex = expf(e - mx);
    float ssum = ex;
#pragma unroll
    for (int m = 1; m < 32; m <<= 1) ssum += __shfl_xor(ssum, m);
    float wgt = ex / ssum;
    float h = 0.f;
#pragma unroll
    for (int k = 0; k < 32; ++k) {
        int ck = __builtin_amdgcn_readlane(col, k);
        float wk = __uint_as_float((unsigned)__builtin_amdgcn_readlane(
            (int)__float_as_uint(wgt), k));
        h += wk * bf2f(M0h[(size_t)ck * DD + lane]);
    }
    float eh = h > 0.f ? h : (expf(h) - 1.f);
    float v = (M0[(size_t)row * DD + lane] + eh) * 0.5f;
    T0[(size_t)(NUM_USERS + row) * DD + lane] = f2bf(v);
}

// ---------- Phase B: in-LDS bucket sort -> rowptr + CSR-ordered sedge ----------
__global__ __launch_bounds__(256) void binB2(const int* __restrict__ bbase,
                                             int2* __restrict__ sedge,
                                             int* __restrict__ rowptr) {
    __shared__ int2 ebuf[BCAP];
    __shared__ int2 obuf[BCAP];
    __shared__ int rc[128];
    __shared__ int ro[128];
    int b = blockIdx.x;
    int tid = threadIdx.x;
    int base = bbase[b];
    int n = min(bbase[b + 1] - base, BCAP);
    for (int i = tid; i < n; i += 256) ebuf[i] = sedge[base + i];
    if (tid < 128) rc[tid] = 0;
    __syncthreads();
    for (int i = tid; i < n; i += 256)
        atomicAdd(&rc[(ebuf[i].x >> 17) & 127], 1);
    __syncthreads();
    if (tid < 128) ro[tid] = rc[tid];
    __syncthreads();
    for (int off = 1; off < 128; off <<= 1) {
        int x = (tid < 128 && tid >= off) ? ro[tid - off] : 0;
        __syncthreads();
        if (tid < 128) ro[tid] += x;
        __syncthreads();
    }
    if (tid < 128) {
        int excl = ro[tid] - rc[tid];
        int gr = (b << 7) + tid;
        if (gr < NTOT) rowptr[gr] = base + excl;
        rc[tid] = excl;
    }
    __syncthreads();
    for (int i = tid; i < n; i += 256) {
        int2 w = ebuf[i];
        int r = (w.x >> 17) & 127;
        int pos = atomicAdd(&rc[r], 1);
        obuf[pos] = make_int2(w.x & 0x1FFFF, w.y);
    }
    __syncthreads();
    for (int i = tid; i < n; i += 256) sedge[base + i] = obuf[i];
}

// ---------- SpMM layer (pull, scalar edge loads): one wave per row ----------
__global__ __launch_bounds__(256) void spmm16(const int* __restrict__ rowptr,
                                              const int2* __restrict__ sedge,
                                              const ushort_t* __restrict__ cur,
                                              ushort_t* __restrict__ nxt) {
    int row = __builtin_amdgcn_readfirstlane((blockIdx.x * 256 + threadIdx.x) >> 6);
    int lane = threadIdx.x & 63;
    if (row >= NTOT) return;
    int i = rowptr[row];
    int e = rowptr[row + 1];
    float acc = 0.f;
    for (; i + 4 <= e; i += 4) {
        int2 ed0 = sedge[i];
        int2 ed1 = sedge[i + 1];
        int2 ed2 = sedge[i + 2];
        int2 ed3 = sedge[i + 3];
        float x0 = bf2f(cur[(size_t)ed0.x * DD + lane]);
        float x1 = bf2f(cur[(size_t)ed1.x * DD + lane]);
        float x2 = bf2f(cur[(size_t)ed2.x * DD + lane]);
        float x3 = bf2f(cur[(size_t)ed3.x * DD + lane]);
        acc += __int_as_float(ed0.y) * x0;
        acc += __int_as_float(ed1.y) * x1;
        acc += __int_as_float(ed2.y) * x2;
        acc += __int_as_float(ed3.y) * x3;
    }
    for (; i < e; ++i) {
        int2 ed = sedge[i];
        acc += __int_as_float(ed.y) * bf2f(cur[(size_t)ed.x * DD + lane]);
    }
    nxt[(size_t)row * DD + lane] = f2bf(acc);
}

// ---------- final: fused layer-3 (only at gathered rows) + sum + dot ----------
// One 128-thread block (2 waves) per batch element: wave0 = user row, wave1 = item row.
__global__ __launch_bounds__(128) void gamma2(const int* __restrict__ users,
                                              const int* __restrict__ items,
                                              const int* __restrict__ rowptr,
                                              const int2* __restrict__ sedge,
                                              const ushort_t* __restrict__ T0,
                                              const ushort_t* __restrict__ T1,
                                              const ushort_t* __restrict__ T2,
                                              float* __restrict__ out) {
    __shared__ float sv[128];
    int b = blockIdx.x;
    int w = threadIdx.x >> 6;
    int lane = threadIdx.x & 63;
    int row = (w == 0) ? users[b] : (NUM_USERS + items[b]);
    row = __builtin_amdgcn_readfirstlane(row);
    size_t o = (size_t)row * DD + lane;
    // layer-3 value at this row: sum_e val_e * T2[col_e]
    float acc = 0.f;
    int i = rowptr[row];
    int e = rowptr[row + 1];
    for (; i + 4 <= e; i += 4) {
        int2 ed0 = sedge[i];
        int2 ed1 = sedge[i + 1];
        int2 ed2 = sedge[i + 2];
        int2 ed3 = sedge[i + 3];
        float x0 = bf2f(T2[(size_t)ed0.x * DD + lane]);
        float x1 = bf2f(T2[(size_t)ed1.x * DD + lane]);
        float x2 = bf2f(T2[(size_t)ed2.x * DD + lane]);
        float x3 = bf2f(T2[(size_t)ed3.x * DD + lane]);
        acc += __int_as_float(ed0.y) * x0;
        acc += __int_as_float(ed1.y) * x1;
        acc += __int_as_float(ed2.y) * x2;
        acc += __int_as_float(ed3.y) * x3;
    }
    for (; i < e; ++i) {
        int2 ed = sedge[i];
        acc += __int_as_float(ed.y) * bf2f(T2[(size_t)ed.x * DD + lane]);
    }
    float s = bf2f(T0[o]) + bf2f(T1[o]) + bf2f(T2[o]) + acc;
    sv[threadIdx.x] = s;
    __syncthreads();
    if (w == 0) {
        float p = sv[lane] * sv[64 + lane];
#pragma unroll
        for (int m = 32; m; m >>= 1) p += __shfl_xor(p, m);
        if (lane == 0) out[b] = p * 0.0625f;
    }
}

extern "C" void kernel_launch(void* const* d_in, const int* in_sizes, int n_in,
                              void* d_out, int out_size, void* d_ws, size_t ws_size,
                              hipStream_t stream) {
    const int* users = (const int*)d_in[0];
    const int* items = (const int*)d_in[1];
    const int* adj = (const int*)d_in[2];
    const int* grows = (const int*)d_in[3];
    const int* gcols = (const int*)d_in[4];
    const float* gvals = (const float*)d_in[5];
    const float* sem = (const float*)d_in[6];
    const float* usem = (const float*)d_in[7];
    const float* emb_user = (const float*)d_in[8];
    const float* emb_item = (const float*)d_in[9];
    const float* W_sem = (const float*)d_in[10];
    const float* b_sem = (const float*)d_in[11];
    const float* W_usem = (const float*)d_in[12];
    const float* b_usem = (const float*)d_in[13];
    const float* W_att = (const float*)d_in[14];
    const float* a_att = (const float*)d_in[15];
    float* out = (float*)d_out;

    const size_t NE = (size_t)NTOT * DD;          // 5.76M
    const size_t IE = (size_t)NUM_ITEMS * DD;     // 1.92M
    char* p = (char*)d_ws;
    ushort_t* T0 = (ushort_t*)p;    p += NE * 2;
    ushort_t* T1 = (ushort_t*)p;    p += NE * 2;
    ushort_t* T2 = (ushort_t*)p;    p += NE * 2;
    ushort_t* T3 = (ushort_t*)p;    p += NE * 2;   // unused (kept for layout stability)
    float* M0 = (float*)p;          p += IE * 4;
    ushort_t* M0h = (ushort_t*)p;   p += IE * 2;
    int2* sedge = (int2*)p;         p += (size_t)NNZE * 8;
    ushort_t* WThiU = (ushort_t*)p; p += 65536 * 2;
    ushort_t* WTloU = (ushort_t*)p; p += 65536 * 2;
    ushort_t* WThiS = (ushort_t*)p; p += 65536 * 2;
    ushort_t* WTloS = (ushort_t*)p; p += 65536 * 2;
    float* s1 = (float*)p;          p += NUM_ITEMS * 4;
    float* s2 = (float*)p;          p += NUM_ITEMS * 4;
    float* wa1 = (float*)p;         p += SEMD * 4;
    float* wa2 = (float*)p;         p += SEMD * 4;
    int* rowptr = (int*)p;          p += (NTOT + 4) * 4;
    int* bcnt = (int*)p;            p += NBKT * 4;
    int* bbase = (int*)p;           p += (NBKT + 1) * 4;
    int* bcursor = (int*)p;         p += NBKT * 4;
    (void)T3;

    hipMemsetAsync(bcnt, 0, NBKT * sizeof(int), stream);
    prep_fused<<<GBH + 513, 256, 0, stream>>>(W_usem, W_sem, WThiU, WTloU, WThiS, WTloS,
                                              W_att, a_att, wa1, wa2, grows, bcnt);

    gemm_mfma<false><<<(NUM_USERS + 63) / 64, 256, 0, stream>>>(
        usem, WThiU, WTloU, b_usem, emb_user, nullptr, T0, NUM_USERS,
        nullptr, nullptr, nullptr, nullptr);
    gemm_mfma<true><<<(NUM_ITEMS + 63) / 64, 256, 0, stream>>>(
        sem, WThiS, WTloS, b_sem, emb_item, M0, M0h, NUM_ITEMS,
        wa1, wa2, s1, s2);

    bscan<<<1, 256, 0, stream>>>(bcnt, bbase, bcursor, rowptr);
    attbin_fused<<<GBH + (NUM_ITEMS * 64 + 255) / 256, 256, 0, stream>>>(
        grows, gcols, gvals, bcursor, sedge, adj, s1, s2, M0, M0h, T0);
    binB2<<<NBKT, 256, 0, stream>>>(bbase, sedge, rowptr);

    // layers 1 and 2 over all rows; layer 3 fused into gamma2 at gathered rows only
    spmm16<<<(NTOT * 64 + 255) / 256, 256, 0, stream>>>(rowptr, sedge, T0, T1);
    spmm16<<<(NTOT * 64 + 255) / 256, 256, 0, stream>>>(rowptr, sedge, T1, T2);

    gamma2<<<BBATCH, 128, 0, stream>>>(users, items, rowptr, sedge, T0, T1, T2, out);
}

// Round 17
// 351.532 us; speedup vs baseline: 1.8690x; 1.0097x over previous
//
#include <hip/hip_runtime.h>
#include <hip/hip_bf16.h>
#include <math.h>

#define NUM_USERS 60000
#define NUM_ITEMS 30000
#define DD 64
#define SEMD 1024
#define HIDD 32
#define KNBR 32
#define NNZE 2000000
#define NLAYERS 3
#define BBATCH 4096
#define LALPHA 0.2f
#define NTOT (NUM_USERS + NUM_ITEMS)
#define NBKT 704                         // buckets = row>>7
#define BCAP 3328                        // bucket LDS cap (+9 sigma)
#define GBH 489                          // bhist/binA grid ((NNZE+4095)/4096)

typedef unsigned short ushort_t;
typedef short s16x8 __attribute__((ext_vector_type(8)));
typedef float f32x4 __attribute__((ext_vector_type(4)));

__device__ __forceinline__ ushort_t f2bf(float x) {  // RNE
    unsigned u = __float_as_uint(x);
    return (ushort_t)((u + 0x7FFFu + ((u >> 16) & 1u)) >> 16);
}
__device__ __forceinline__ float bf2f(ushort_t s) {
    return __uint_as_float(((unsigned)s) << 16);
}

#define CFENCE() asm volatile("" ::: "memory")

// ---------- fused: bhist (bid<GBH) | wsplit (GBH..GBH+511) | prep_wa (last) ----------
__global__ __launch_bounds__(256) void prep_fused(
    const float* __restrict__ Wu, const float* __restrict__ Ws,
    ushort_t* __restrict__ hiU, ushort_t* __restrict__ loU,
    ushort_t* __restrict__ hiS, ushort_t* __restrict__ loS,
    const float* __restrict__ W_att, const float* __restrict__ a_att,
    float* __restrict__ wa1, float* __restrict__ wa2,
    const int* __restrict__ grows, int* __restrict__ bcnt) {
    __shared__ int h[NBKT];
    int tid = threadIdx.x;
    int bid = blockIdx.x;
    if (bid < GBH) {   // bhist
        int base = bid * 4096;
        for (int i = tid; i < NBKT; i += 256) h[i] = 0;
        __syncthreads();
#pragma unroll 4
        for (int j = 0; j < 16; ++j) {
            int e = base + j * 256 + tid;
            if (e < NNZE) atomicAdd(&h[grows[e] >> 7], 1);
        }
        __syncthreads();
        for (int b = tid; b < NBKT; b += 256)
            if (h[b]) atomicAdd(&bcnt[b], h[b]);
        return;
    }
    if (bid == GBH + 512) {   // prep_wa
#pragma unroll
        for (int r = 0; r < 4; ++r) {
            int k = tid * 4 + r;
            float d1 = 0.f, d2 = 0.f;
#pragma unroll
            for (int hh = 0; hh < HIDD; ++hh) {
                float w = W_att[k * HIDD + hh];
                d1 += w * a_att[hh];
                d2 += w * a_att[HIDD + hh];
            }
            wa1[k] = d1;
            wa2[k] = d2;
        }
        return;
    }
    // wsplit
    int id = (bid - GBH) * 256 + tid;  // 0..131071
    int i = id & 65535;
    int k = i & 1023;
    int c = i >> 10;
    float x = (id < 65536) ? Wu[(size_t)k * DD + c] : Ws[(size_t)k * DD + c];
    ushort_t hh = f2bf(x);
    ushort_t ll = f2bf(x - bf2f(hh));
    ushort_t* dh = (id < 65536) ? hiU : hiS;
    ushort_t* dl = (id < 65536) ? loU : loS;
    dh[(size_t)c * SEMD + k] = hh;
    dl[(size_t)c * SEMD + k] = ll;
}

// ---------- MFMA bf16x3 GEMM: R5 structure + 2-deep A register pipeline ----------
#define LOAD_A(KT, RA)                                                          \
    _Pragma("unroll")                                                           \
    for (int p = 0; p < 4; ++p) {                                               \
        int grow_ = row0 + p * 16 + srow;                                       \
        RA[p] = make_float4(0.f, 0.f, 0.f, 0.f);                                \
        if (grow_ < M)                                                          \
            RA[p] = *(const float4*)(A + (size_t)grow_ * SEMD + (KT) * 64 + sc * 4); \
    }

#define LOAD_W(KT)                                                              \
    {                                                                           \
        const ushort_t* sh_ = WThi + (size_t)wcol * SEMD + (KT) * 64 + wq * 16; \
        const ushort_t* sl_ = WTlo + (size_t)wcol * SEMD + (KT) * 64 + wq * 16; \
        rWh[0] = *(const s16x8*)sh_;                                            \
        rWh[1] = *(const s16x8*)(sh_ + 8);                                      \
        rWl[0] = *(const s16x8*)sl_;                                            \
        rWl[1] = *(const s16x8*)(sl_ + 8);                                      \
    }

#define GEMM_STEP(KT, RA)                                                       \
    {                                                                           \
        float4 va1w, va2w;                                                      \
        if (DOS12) {                                                            \
            va1w = *(const float4*)(wa1 + (KT) * 64 + sc * 4);                  \
            va2w = *(const float4*)(wa2 + (KT) * 64 + sc * 4);                  \
        }                                                                       \
        CFENCE();                                                               \
        __builtin_amdgcn_s_barrier();                                           \
        CFENCE();                                                               \
        _Pragma("unroll")                                                       \
        for (int p = 0; p < 4; ++p) {                                           \
            float4 v = RA[p];                                                   \
            if (DOS12) {                                                        \
                s1p[p] += v.x * va1w.x + v.y * va1w.y + v.z * va1w.z + v.w * va1w.w; \
                s2p[p] += v.x * va2w.x + v.y * va2w.y + v.z * va2w.z + v.w * va2w.w; \
            }                                                                   \
            unsigned ux = __float_as_uint(v.x), uy = __float_as_uint(v.y);      \
            unsigned uz = __float_as_uint(v.z), uw = __float_as_uint(v.w);      \
            ushort4 hv, lv;                                                     \
            hv.x = (ushort_t)(ux >> 16); hv.y = (ushort_t)(uy >> 16);           \
            hv.z = (ushort_t)(uz >> 16); hv.w = (ushort_t)(uw >> 16);           \
            lv.x = (ushort_t)(__float_as_uint(v.x - __uint_as_float(ux & 0xFFFF0000u)) >> 16); \
            lv.y = (ushort_t)(__float_as_uint(v.y - __uint_as_float(uy & 0xFFFF0000u)) >> 16); \
            lv.z = (ushort_t)(__float_as_uint(v.z - __uint_as_float(uz & 0xFFFF0000u)) >> 16); \
            lv.w = (ushort_t)(__float_as_uint(v.w - __uint_as_float(uw & 0xFFFF0000u)) >> 16); \
            int rin_ = p * 16 + srow;                                           \
            int boff_ = rin_ * 128 + ((sc * 8) ^ ((rin_ & 7) << 4));            \
            *(ushort4*)((char*)Ah + boff_) = hv;                                \
            *(ushort4*)((char*)Alo + boff_) = lv;                               \
        }                                                                       \
        {                                                                       \
            char* dh_ = (char*)Wh + wcol * 128;                                 \
            char* dl_ = (char*)Wl + wcol * 128;                                 \
            int sw_ = (wcol & 7) << 4;                                          \
            *(s16x8*)(dh_ + ((wq * 32) ^ sw_)) = rWh[0];                        \
            *(s16x8*)(dh_ + ((wq * 32 + 16) ^ sw_)) = rWh[1];                   \
            *(s16x8*)(dl_ + ((wq * 32) ^ sw_)) = rWl[0];                        \
            *(s16x8*)(dl_ + ((wq * 32 + 16) ^ sw_)) = rWl[1];                   \
        }                                                                       \
        if ((KT) + 2 < 16) { LOAD_A((KT) + 2, RA) }                             \
        if ((KT) + 1 < 16) { LOAD_W((KT) + 1) }                                 \
        asm volatile("s_waitcnt lgkmcnt(0)" ::: "memory");                      \
        __builtin_amdgcn_s_barrier();                                           \
        CFENCE();                                                               \
        s16x8 fah[2], fal[2];                                                   \
        _Pragma("unroll")                                                       \
        for (int kf = 0; kf < 2; ++kf) {                                        \
            int row_ = w * 16 + l15;                                            \
            int bc_ = kf * 64 + l4 * 16;                                        \
            int off_ = row_ * 128 + (bc_ ^ ((row_ & 7) << 4));                  \
            fah[kf] = *(const s16x8*)((const char*)Ah + off_);                  \
            fal[kf] = *(const s16x8*)((const char*)Alo + off_);                 \
        }                                                                       \
        _Pragma("unroll")                                                       \
        for (int cg = 0; cg < 4; ++cg) {                                        \
            s16x8 fwh[2], fwl[2];                                               \
            _Pragma("unroll")                                                   \
            for (int kf = 0; kf < 2; ++kf) {                                    \
                int col_ = cg * 16 + l15;                                       \
                int bc_ = kf * 64 + l4 * 16;                                    \
                int off_ = col_ * 128 + (bc_ ^ ((col_ & 7) << 4));              \
                fwh[kf] = *(const s16x8*)((const char*)Wh + off_);              \
                fwl[kf] = *(const s16x8*)((const char*)Wl + off_);              \
            }                                                                   \
            _Pragma("unroll")                                                   \
            for (int kf = 0; kf < 2; ++kf) {                                    \
                acc[cg] = __builtin_amdgcn_mfma_f32_16x16x32_bf16(fah[kf], fwh[kf], acc[cg], 0, 0, 0); \
                acc[cg] = __builtin_amdgcn_mfma_f32_16x16x32_bf16(fah[kf], fwl[kf], acc[cg], 0, 0, 0); \
                acc[cg] = __builtin_amdgcn_mfma_f32_16x16x32_bf16(fal[kf], fwh[kf], acc[cg], 0, 0, 0); \
            }                                                                   \
        }                                                                       \
    }

template <bool DOS12>
__global__ __launch_bounds__(256) void gemm_mfma(
    const float* __restrict__ A,
    const ushort_t* __restrict__ WThi,
    const ushort_t* __restrict__ WTlo,
    const float* __restrict__ bias,
    const float* __restrict__ emb,
    float* __restrict__ out32,       // only written when DOS12 (items: M0)
    ushort_t* __restrict__ out16,
    int M,
    const float* __restrict__ wa1,
    const float* __restrict__ wa2,
    float* __restrict__ s1,
    float* __restrict__ s2) {
    __shared__ __align__(16) ushort_t Ah[64 * 64];
    __shared__ __align__(16) ushort_t Alo[64 * 64];
    __shared__ __align__(16) ushort_t Wh[64 * 64];
    __shared__ __align__(16) ushort_t Wl[64 * 64];

    const int tid = threadIdx.x;
    const int lane = tid & 63;
    const int w = tid >> 6;
    const int l15 = lane & 15;
    const int l4 = lane >> 4;
    const int row0 = blockIdx.x * 64;

    f32x4 acc[4] = {};
    float s1p[4] = {}, s2p[4] = {};

    const int srow = tid >> 4;
    const int sc = tid & 15;
    const int wcol = tid >> 2;
    const int wq = tid & 3;

    float4 rA0[4], rA1[4];
    s16x8 rWh[2], rWl[2];

    LOAD_A(0, rA0)
    LOAD_A(1, rA1)
    LOAD_W(0)

    for (int kt = 0; kt < 16; kt += 2) {
        GEMM_STEP(kt, rA0)
        GEMM_STEP(kt + 1, rA1)
    }

    if (DOS12) {
#pragma unroll
        for (int p = 0; p < 4; ++p) {
            float v1 = s1p[p], v2 = s2p[p];
#pragma unroll
            for (int m = 1; m < 16; m <<= 1) {
                v1 += __shfl_xor(v1, m);
                v2 += __shfl_xor(v2, m);
            }
            int grow = row0 + p * 16 + srow;
            if (sc == 0 && grow < M) {
                s1[grow] = v1;
                s2[grow] = v2;
            }
        }
    }

#pragma unroll
    for (int cg = 0; cg < 4; ++cg) {
        int col = cg * 16 + l15;
        float b = bias[col];
#pragma unroll
        for (int j = 0; j < 4; ++j) {
            int grow = row0 + w * 16 + l4 * 4 + j;
            if (grow < M) {
                float x = acc[cg][j] + b;
                float e = x > 0.f ? x : (expf(x) - 1.f);
                float v = (emb[(size_t)grow * DD + col] + e) * 0.5f;
                if (DOS12) out32[(size_t)grow * DD + col] = v;
                out16[(size_t)grow * DD + col] = f2bf(v);
            }
        }
    }
}

// ---------- bucket scan: bases for binA + total ----------
__global__ __launch_bounds__(256) void bscan(const int* __restrict__ bcnt,
                                             int* __restrict__ bbase,
                                             int* __restrict__ bcursor,
                                             int* __restrict__ rowptr) {
    __shared__ int part[256];
    int t = threadIdx.x;
    int loc[3];
    int s = 0;
#pragma unroll
    for (int i = 0; i < 3; ++i) {
        int idx = t * 3 + i;
        int v = (idx < NBKT) ? bcnt[idx] : 0;
        loc[i] = v;
        s += v;
    }
    part[t] = s;
    __syncthreads();
    for (int off = 1; off < 256; off <<= 1) {
        int x = (t >= off) ? part[t - off] : 0;
        __syncthreads();
        part[t] += x;
        __syncthreads();
    }
    int excl = t ? part[t - 1] : 0;
#pragma unroll
    for (int i = 0; i < 3; ++i) {
        int idx = t * 3 + i;
        if (idx < NBKT) {
            bbase[idx] = excl;
            bcursor[idx] = excl;
            excl += loc[i];
        }
    }
    if (t == 255) {
        bbase[NBKT] = part[255];
        rowptr[NTOT] = part[255];
    }
}

// ---------- fused: binA (bid<GBH) | att (rest) ----------
__global__ __launch_bounds__(256) void attbin_fused(
    const int* __restrict__ grows, const int* __restrict__ gcols,
    const float* __restrict__ gvals, int* __restrict__ bcursor,
    int2* __restrict__ sedge,
    const int* __restrict__ adj, const float* __restrict__ s1,
    const float* __restrict__ s2, const float* __restrict__ M0,
    const ushort_t* __restrict__ M0h, ushort_t* __restrict__ T0) {
    __shared__ int hist[NBKT];
    __shared__ int gcur[NBKT];
    int tid = threadIdx.x;
    int bid = blockIdx.x;
    if (bid < GBH) {   // binA
        int base = bid * 4096;
        for (int i = tid; i < NBKT; i += 256) hist[i] = 0;
        __syncthreads();
#pragma unroll 4
        for (int j = 0; j < 16; ++j) {
            int e = base + j * 256 + tid;
            if (e < NNZE) atomicAdd(&hist[grows[e] >> 7], 1);
        }
        __syncthreads();
        for (int b = tid; b < NBKT; b += 256) {
            int n = hist[b];
            gcur[b] = n ? atomicAdd(&bcursor[b], n) : 0;
        }
        __syncthreads();
#pragma unroll 4
        for (int j = 0; j < 16; ++j) {
            int e = base + j * 256 + tid;
            if (e < NNZE) {
                int r = grows[e];
                int b = r >> 7;
                int pos = atomicAdd(&gcur[b], 1);
                sedge[pos] = make_int2((gcols[e] & 0x1FFFF) | ((r & 127) << 17),
                                       __float_as_int(gvals[e]));
            }
        }
        return;
    }
    // att
    int gid = (bid - GBH) * 256 + tid;
    int row = gid >> 6;
    int lane = gid & 63;
    if (row >= NUM_ITEMS) return;
    int kk = lane & 31;
    int col = adj[(size_t)row * KNBR + kk];
    float e = s1[col] + s2[row];
    e = e > 0.f ? e : LALPHA * e;
    float mx = e;
#pragma unroll
    for (int m = 1; m < 32; m <<= 1) mx = fmaxf(mx, __shfl_xor(mx, m));
    float ex = expf(e - mx);
    float ssum = ex;
#pragma unroll
    for (int m = 1; m < 32; m <<= 1) ssum += __shfl_xor(ssum, m);
    float wgt = ex / ssum;
    float h = 0.f;
#pragma unroll
    for (int k = 0; k < 32; ++k) {
        int ck = __builtin_amdgcn_readlane(col, k);
        float wk = __uint_as_float((unsigned)__builtin_amdgcn_readlane(
            (int)__float_as_uint(wgt), k));
        h += wk * bf2f(M0h[(size_t)ck * DD + lane]);
    }
    float eh = h > 0.f ? h : (expf(h) - 1.f);
    float v = (M0[(size_t)row * DD + lane] + eh) * 0.5f;
    T0[(size_t)(NUM_USERS + row) * DD + lane] = f2bf(v);
}

// ---------- Phase B: in-LDS bucket sort -> rowptr + CSR-ordered sedge ----------
__global__ __launch_bounds__(256) void binB2(const int* __restrict__ bbase,
                                             int2* __restrict__ sedge,
                                             int* __restrict__ rowptr) {
    __shared__ int2 ebuf[BCAP];
    __shared__ int2 obuf[BCAP];
    __shared__ int rc[128];
    __shared__ int ro[128];
    int b = blockIdx.x;
    int tid = threadIdx.x;
    int base = bbase[b];
    int n = min(bbase[b + 1] - base, BCAP);
    for (int i = tid; i < n; i += 256) ebuf[i] = sedge[base + i];
    if (tid < 128) rc[tid] = 0;
    __syncthreads();
    for (int i = tid; i < n; i += 256)
        atomicAdd(&rc[(ebuf[i].x >> 17) & 127], 1);
    __syncthreads();
    if (tid < 128) ro[tid] = rc[tid];
    __syncthreads();
    for (int off = 1; off < 128; off <<= 1) {
        int x = (tid < 128 && tid >= off) ? ro[tid - off] : 0;
        __syncthreads();
        if (tid < 128) ro[tid] += x;
        __syncthreads();
    }
    if (tid < 128) {
        int excl = ro[tid] - rc[tid];
        int gr = (b << 7) + tid;
        if (gr < NTOT) rowptr[gr] = base + excl;
        rc[tid] = excl;
    }
    __syncthreads();
    for (int i = tid; i < n; i += 256) {
        int2 w = ebuf[i];
        int r = (w.x >> 17) & 127;
        int pos = atomicAdd(&rc[r], 1);
        obuf[pos] = make_int2(w.x & 0x1FFFF, w.y);
    }
    __syncthreads();
    for (int i = tid; i < n; i += 256) sedge[base + i] = obuf[i];
}

// ---------- SpMM layer (pull, scalar edge loads): one wave per row ----------
__global__ __launch_bounds__(256) void spmm16(const int* __restrict__ rowptr,
                                              const int2* __restrict__ sedge,
                                              const ushort_t* __restrict__ cur,
                                              ushort_t* __restrict__ nxt) {
    int row = __builtin_amdgcn_readfirstlane((blockIdx.x * 256 + threadIdx.x) >> 6);
    int lane = threadIdx.x & 63;
    if (row >= NTOT) return;
    int i = rowptr[row];
    int e = rowptr[row + 1];
    float acc = 0.f;
    for (; i + 4 <= e; i += 4) {
        int2 ed0 = sedge[i];
        int2 ed1 = sedge[i + 1];
        int2 ed2 = sedge[i + 2];
        int2 ed3 = sedge[i + 3];
        float x0 = bf2f(cur[(size_t)ed0.x * DD + lane]);
        float x1 = bf2f(cur[(size_t)ed1.x * DD + lane]);
        float x2 = bf2f(cur[(size_t)ed2.x * DD + lane]);
        float x3 = bf2f(cur[(size_t)ed3.x * DD + lane]);
        acc += __int_as_float(ed0.y) * x0;
        acc += __int_as_float(ed1.y) * x1;
        acc += __int_as_float(ed2.y) * x2;
        acc += __int_as_float(ed3.y) * x3;
    }
    for (; i < e; ++i) {
        int2 ed = sedge[i];
        acc += __int_as_float(ed.y) * bf2f(cur[(size_t)ed.x * DD + lane]);
    }
    nxt[(size_t)row * DD + lane] = f2bf(acc);
}

// ---------- final: fused layer-3 (only at gathered rows) + sum + dot ----------
// One 128-thread block (2 waves) per batch element: wave0 = user row, wave1 = item row.
__global__ __launch_bounds__(128) void gamma2(const int* __restrict__ users,
                                              const int* __restrict__ items,
                                              const int* __restrict__ rowptr,
                                              const int2* __restrict__ sedge,
                                              const ushort_t* __restrict__ T0,
                                              const ushort_t* __restrict__ T1,
                                              const ushort_t* __restrict__ T2,
                                              float* __restrict__ out) {
    __shared__ float sv[128];
    int b = blockIdx.x;
    int w = threadIdx.x >> 6;
    int lane = threadIdx.x & 63;
    int row = (w == 0) ? users[b] : (NUM_USERS + items[b]);
    row = __builtin_amdgcn_readfirstlane(row);
    size_t o = (size_t)row * DD + lane;
    // layer-3 value at this row: sum_e val_e * T2[col_e]
    float acc = 0.f;
    int i = rowptr[row];
    int e = rowptr[row + 1];
    for (; i + 4 <= e; i += 4) {
        int2 ed0 = sedge[i];
        int2 ed1 = sedge[i + 1];
        int2 ed2 = sedge[i + 2];
        int2 ed3 = sedge[i + 3];
        float x0 = bf2f(T2[(size_t)ed0.x * DD + lane]);
        float x1 = bf2f(T2[(size_t)ed1.x * DD + lane]);
        float x2 = bf2f(T2[(size_t)ed2.x * DD + lane]);
        float x3 = bf2f(T2[(size_t)ed3.x * DD + lane]);
        acc += __int_as_float(ed0.y) * x0;
        acc += __int_as_float(ed1.y) * x1;
        acc += __int_as_float(ed2.y) * x2;
        acc += __int_as_float(ed3.y) * x3;
    }
    for (; i < e; ++i) {
        int2 ed = sedge[i];
        acc += __int_as_float(ed.y) * bf2f(T2[(size_t)ed.x * DD + lane]);
    }
    float s = bf2f(T0[o]) + bf2f(T1[o]) + bf2f(T2[o]) + acc;
    sv[threadIdx.x] = s;
    __syncthreads();
    if (w == 0) {
        float p = sv[lane] * sv[64 + lane];
#pragma unroll
        for (int m = 32; m; m >>= 1) p += __shfl_xor(p, m);
        if (lane == 0) out[b] = p * 0.0625f;
    }
}

extern "C" void kernel_launch(void* const* d_in, const int* in_sizes, int n_in,
                              void* d_out, int out_size, void* d_ws, size_t ws_size,
                              hipStream_t stream) {
    const int* users = (const int*)d_in[0];
    const int* items = (const int*)d_in[1];
    const int* adj = (const int*)d_in[2];
    const int* grows = (const int*)d_in[3];
    const int* gcols = (const int*)d_in[4];
    const float* gvals = (const float*)d_in[5];
    const float* sem = (const float*)d_in[6];
    const float* usem = (const float*)d_in[7];
    const float* emb_user = (const float*)d_in[8];
    const float* emb_item = (const float*)d_in[9];
    const float* W_sem = (const float*)d_in[10];
    const float* b_sem = (const float*)d_in[11];
    const float* W_usem = (const float*)d_in[12];
    const float* b_usem = (const float*)d_in[13];
    const float* W_att = (const float*)d_in[14];
    const float* a_att = (const float*)d_in[15];
    float* out = (float*)d_out;

    const size_t NE = (size_t)NTOT * DD;          // 5.76M
    const size_t IE = (size_t)NUM_ITEMS * DD;     // 1.92M
    char* p = (char*)d_ws;
    ushort_t* T0 = (ushort_t*)p;    p += NE * 2;
    ushort_t* T1 = (ushort_t*)p;    p += NE * 2;
    ushort_t* T2 = (ushort_t*)p;    p += NE * 2;
    ushort_t* T3 = (ushort_t*)p;    p += NE * 2;   // unused (kept for layout stability)
    float* M0 = (float*)p;          p += IE * 4;
    ushort_t* M0h = (ushort_t*)p;   p += IE * 2;
    int2* sedge = (int2*)p;         p += (size_t)NNZE * 8;
    ushort_t* WThiU = (ushort_t*)p; p += 65536 * 2;
    ushort_t* WTloU = (ushort_t*)p; p += 65536 * 2;
    ushort_t* WThiS = (ushort_t*)p; p += 65536 * 2;
    ushort_t* WTloS = (ushort_t*)p; p += 65536 * 2;
    float* s1 = (float*)p;          p += NUM_ITEMS * 4;
    float* s2 = (float*)p;          p += NUM_ITEMS * 4;
    float* wa1 = (float*)p;         p += SEMD * 4;
    float* wa2 = (float*)p;         p += SEMD * 4;
    int* rowptr = (int*)p;          p += (NTOT + 4) * 4;
    int* bcnt = (int*)p;            p += NBKT * 4;
    int* bbase = (int*)p;           p += (NBKT + 1) * 4;
    int* bcursor = (int*)p;         p += NBKT * 4;
    (void)T3;

    hipMemsetAsync(bcnt, 0, NBKT * sizeof(int), stream);
    prep_fused<<<GBH + 513, 256, 0, stream>>>(W_usem, W_sem, WThiU, WTloU, WThiS, WTloS,
                                              W_att, a_att, wa1, wa2, grows, bcnt);

    gemm_mfma<false><<<(NUM_USERS + 63) / 64, 256, 0, stream>>>(
        usem, WThiU, WTloU, b_usem, emb_user, nullptr, T0, NUM_USERS,
        nullptr, nullptr, nullptr, nullptr);
    gemm_mfma<true><<<(NUM_ITEMS + 63) / 64, 256, 0, stream>>>(
        sem, WThiS, WTloS, b_sem, emb_item, M0, M0h, NUM_ITEMS,
        wa1, wa2, s1, s2);

    bscan<<<1, 256, 0, stream>>>(bcnt, bbase, bcursor, rowptr);
    attbin_fused<<<GBH + (NUM_ITEMS * 64 + 255) / 256, 256, 0, stream>>>(
        grows, gcols, gvals, bcursor, sedge, adj, s1, s2, M0, M0h, T0);
    binB2<<<NBKT, 256, 0, stream>>>(bbase, sedge, rowptr);

    // layers 1 and 2 over all rows; layer 3 fused into gamma2 at gathered rows only
    spmm16<<<(NTOT * 64 + 255) / 256, 256, 0, stream>>>(rowptr, sedge, T0, T1);
    spmm16<<<(NTOT * 64 + 255) / 256, 256, 0, stream>>>(rowptr, sedge, T1, T2);

    gamma2<<<BBATCH, 128, 0, stream>>>(users, items, rowptr, sedge, T0, T1, T2, out);
}